// Round 4
// baseline (458.420 us; speedup 1.0000x reference)
//
#include <hip/hip_runtime.h>

typedef _Float16 f16_t;
typedef float f32x4 __attribute__((ext_vector_type(4)));
typedef _Float16 f16x8 __attribute__((ext_vector_type(8)));

#define AS1 __attribute__((address_space(1)))
#define AS3 __attribute__((address_space(3)))

__device__ __forceinline__ void gload_lds16(const void* g, void* l) {
  __builtin_amdgcn_global_load_lds((const AS1 void*)g, (AS3 void*)l, 16, 0, 0);
}

// ------------- adj = softmax(relu(E E^T), axis=1), single fp16 plane -------
// Stored pre-scaled by 2^12 so tiny softmax entries stay out of the fp16
// denormal range; fgemm epilogue multiplies by 2^-12.
__global__ __launch_bounds__(256) void adj_softmax(const float* __restrict__ emb,
                                                   f16_t* __restrict__ adjF) {
  __shared__ float vals[2048];
  __shared__ float red[16];
  const int n = blockIdx.x;
  const int t = threadIdx.x;
  const int lane = t & 63, wave = t >> 6;
  float en[10];
#pragma unroll
  for (int e = 0; e < 10; ++e) en[e] = emb[n * 10 + e];
  float lm = 0.0f;
  for (int m = t; m < 2048; m += 256) {
    const float* em = emb + m * 10;
    float d = 0.f;
#pragma unroll
    for (int e = 0; e < 10; ++e) d += en[e] * em[e];
    d = fmaxf(d, 0.0f);
    vals[m] = d;
    lm = fmaxf(lm, d);
  }
#pragma unroll
  for (int off = 32; off > 0; off >>= 1) lm = fmaxf(lm, __shfl_down(lm, off));
  if (lane == 0) red[wave] = lm;
  __syncthreads();
  const float gmax = fmaxf(fmaxf(red[0], red[1]), fmaxf(red[2], red[3]));
  float ls = 0.f;
  for (int m = t; m < 2048; m += 256) {
    float ev = expf(vals[m] - gmax);
    vals[m] = ev;
    ls += ev;
  }
#pragma unroll
  for (int off = 32; off > 0; off >>= 1) ls += __shfl_down(ls, off);
  if (lane == 0) red[8 + wave] = ls;
  __syncthreads();
  const float inv = 4096.0f / (red[8] + red[9] + red[10] + red[11]);
  for (int m = t; m < 2048; m += 256) {
    adjF[(long)n * 2048 + m] = (f16_t)(vals[m] * inv);
  }
}

// ------------- XT[b*64+i][m] = x[b][m][i], fp16 hi/lo planes ---------------
__global__ __launch_bounds__(256) void split_xt(const float* __restrict__ x,
                                                f16_t* __restrict__ XTh,
                                                f16_t* __restrict__ XTl) {
  __shared__ float tile[64][65];
  const int m0 = blockIdx.x * 64;
  const int b = blockIdx.y;
  const int tx = threadIdx.x & 63, ty = threadIdx.x >> 6;
  for (int r = ty; r < 64; r += 4)
    tile[r][tx] = x[(long)b * 131072 + (long)(m0 + r) * 64 + tx];
  __syncthreads();
  for (int r = ty; r < 64; r += 4) {
    float v = tile[tx][r];
    f16_t h = (f16_t)v;
    long idx = (long)(b * 64 + r) * 2048 + m0 + tx;
    XTh[idx] = h;
    XTl[idx] = (f16_t)(v - (float)h);
  }
}

// ------------- generic fp32 transpose-split: out[c][r] = in[r][c] ----------
__global__ __launch_bounds__(256) void tsplit(const float* __restrict__ in,
                                              f16_t* __restrict__ oH,
                                              f16_t* __restrict__ oL, int R, int C) {
  __shared__ float tile[64][65];
  const int c0 = blockIdx.x * 64, r0 = blockIdx.y * 64;
  const int tx = threadIdx.x & 63, ty = threadIdx.x >> 6;
  for (int r = ty; r < 64; r += 4)
    tile[r][tx] = in[(long)(r0 + r) * C + c0 + tx];
  __syncthreads();
  for (int r = ty; r < 64; r += 4) {
    float v = tile[tx][r];
    f16_t h = (f16_t)v;
    long idx = (long)(c0 + r) * R + r0 + tx;
    oH[idx] = h;
    oL[idx] = (f16_t)(v - (float)h);
  }
}

// ------------- permute w_pool (E,3,I,O) -> P[e][o*KI + k*I+i], fp32 --------
__global__ __launch_bounds__(256) void permute_pool(const float* __restrict__ wp,
                                                    float* __restrict__ P,
                                                    int KI, int I, int O) {
  const int g = blockIdx.x * 256 + threadIdx.x;
  const int per = KI * O;  // 24576
  const int e = g / per, rem = g % per;
  const int o = rem / KI, kk = rem % KI;
  const int k = kk / I, i = kk % I;
  P[g] = wp[(long)((e * 3 + k) * I + i) * O + o];
}

// ------------- W[n][c] = fp16(sum_e emb[n,e] * P[e][c]) — 96 MiB out -------
__global__ __launch_bounds__(256) void wgen(const float* __restrict__ P,
                                            const float* __restrict__ emb,
                                            f16_t* __restrict__ W) {
  __shared__ float Ps[10 * 1024];
  __shared__ float es[160];
  const int c0 = blockIdx.x * 1024;
  const int n0 = blockIdx.y * 16;
  const int t = threadIdx.x;
  for (int g = t; g < 10240; g += 256) {
    int e = g >> 10, idx = g & 1023;
    Ps[g] = P[(long)e * 24576 + c0 + idx];
  }
  if (t < 160) es[t] = emb[n0 * 10 + t];
  __syncthreads();
  for (int nn = 0; nn < 16; ++nn) {
    float e0 = es[nn * 10 + 0], e1 = es[nn * 10 + 1], e2 = es[nn * 10 + 2],
          e3 = es[nn * 10 + 3], e4 = es[nn * 10 + 4], e5 = es[nn * 10 + 5],
          e6 = es[nn * 10 + 6], e7 = es[nn * 10 + 7], e8 = es[nn * 10 + 8],
          e9 = es[nn * 10 + 9];
#pragma unroll
    for (int q = 0; q < 4; ++q) {
      int idx = q * 256 + t;
      float v = e0 * Ps[idx] + e1 * Ps[1024 + idx] + e2 * Ps[2048 + idx] +
                e3 * Ps[3072 + idx] + e4 * Ps[4096 + idx] + e5 * Ps[5120 + idx] +
                e6 * Ps[6144 + idx] + e7 * Ps[7168 + idx] + e8 * Ps[8192 + idx] +
                e9 * Ps[9216 + idx];
      W[(long)(n0 + nn) * 24576 + c0 + idx] = (f16_t)v;
    }
  }
}

// ------------- staging helper for fgemm (one BK=64 tile into one buffer) ---
// 12 gload_lds16/thread.  LDS[row][slot s] holds global granule s^(row&7);
// achieved by pre-swizzling the GLOBAL source granule (linear LDS dest).
__device__ __forceinline__ void stage_tile(const f16_t* __restrict__ A,
                                           const f16_t* __restrict__ Bh,
                                           const f16_t* __restrict__ Bl,
                                           f16_t* ash, f16_t* bsh, f16_t* bsl,
                                           long m0, long n0, long K, long k0,
                                           int srow, int sc8, int wave) {
  char* lA = (char*)ash + wave * 1024;
  char* lB = (char*)bsh + wave * 1024;
  char* lC = (char*)bsl + wave * 1024;
#pragma unroll
  for (int q = 0; q < 4; ++q)
    gload_lds16(A + (m0 + q * 32 + srow) * K + k0 + sc8, lA + q * 4096);
#pragma unroll
  for (int q = 0; q < 4; ++q)
    gload_lds16(Bh + (n0 + q * 32 + srow) * K + k0 + sc8, lB + q * 4096);
#pragma unroll
  for (int q = 0; q < 4; ++q)
    gload_lds16(Bl + (n0 + q * 32 + srow) * K + k0 + sc8, lC + q * 4096);
}

// ------------- unified fused GEMM (fp16) v4 --------------------------------
// Block 128(M)x128(N), 4 waves as 2x2, wave tile 64x64 (acc[4][4]).
// Rationale (round-3 post-mortem): kernel is LDS-read-BW-bound; 64x64 wave
// tiles cut ds_read_b128 per MFMA from 0.625 to 0.375.  Grid 16x16 = 256
// blocks = 1 block/CU, so double-buffered staging is load-bearing here
// (no partner block to cover the vmcnt(0) drain; prefetch covers it).
// BK=64, 8-slot XOR swizzle (2-way bank aliasing = free).  A = adj single
// fp16 plane (pre-scaled 2^12), B = fp16 hi/lo.  No XCD swizzle: natural
// order gives each XCD 2 n-panels (2 MB B, L2-fits) and streams A.
// WT: also emit transposed hi/lo split of C (next GEMM's B operand).
template <int WT>
__global__ __launch_bounds__(256, 1) void fgemm(const f16_t* __restrict__ A,
                                                const f16_t* __restrict__ Bh,
                                                const f16_t* __restrict__ Bl,
                                                float* __restrict__ Cf,
                                                f16_t* __restrict__ Th,
                                                f16_t* __restrict__ Tl,
                                                int K, int ldc) {
  __shared__ __align__(16) f16_t Ash[2][128 * 64];
  __shared__ __align__(16) f16_t Bsh[2][128 * 64];
  __shared__ __align__(16) f16_t Bsl[2][128 * 64];
  const int t = threadIdx.x;
  const int wave = t >> 6, lane = t & 63;
  const long n0 = (long)blockIdx.x * 128;
  const long m0 = (long)blockIdx.y * 128;
  const int srow = t >> 3;                       // 0..31 (staging row in chunk)
  const int sc8 = ((t & 7) ^ (srow & 7)) << 3;   // pre-swizzled source granule
  const int fr = lane & 15;
  const int quad = lane >> 4;
  const int wr = wave >> 1, wc = wave & 1;       // 2x2 wave grid
  const int mB = wr * 64, nB = wc * 64;
  f32x4 acc[4][4] = {};

  stage_tile(A, Bh, Bl, Ash[0], Bsh[0], Bsl[0], m0, n0, K, 0, srow, sc8, wave);
  __syncthreads();
  const int NT = K >> 6;
  for (int it = 0; it < NT; ++it) {
    const int bi = it & 1;
    if (it + 1 < NT)
      stage_tile(A, Bh, Bl, Ash[bi ^ 1], Bsh[bi ^ 1], Bsl[bi ^ 1], m0, n0, K,
                 (long)(it + 1) << 6, srow, sc8, wave);
    const f16_t* As = Ash[bi];
    const f16_t* Bs = Bsh[bi];
    const f16_t* Bls = Bsl[bi];
#pragma unroll
    for (int kh = 0; kh < 2; ++kh) {
      const int cbase = kh * 4 + quad;           // granule 0..7
      const int so = ((cbase ^ (fr & 7)) << 3);  // swizzled slot (f16 units)
      f16x8 ah[4], bh[4], bl[4];
#pragma unroll
      for (int i = 0; i < 4; ++i)
        ah[i] = *(const f16x8*)(As + (mB + i * 16 + fr) * 64 + so);
#pragma unroll
      for (int j = 0; j < 4; ++j) {
        bh[j] = *(const f16x8*)(Bs + (nB + j * 16 + fr) * 64 + so);
        bl[j] = *(const f16x8*)(Bls + (nB + j * 16 + fr) * 64 + so);
      }
#pragma unroll
      for (int i = 0; i < 4; ++i)
#pragma unroll
        for (int j = 0; j < 4; ++j)
          acc[i][j] = __builtin_amdgcn_mfma_f32_16x16x32_f16(ah[i], bh[j], acc[i][j], 0, 0, 0);
#pragma unroll
      for (int i = 0; i < 4; ++i)
#pragma unroll
        for (int j = 0; j < 4; ++j)
          acc[i][j] = __builtin_amdgcn_mfma_f32_16x16x32_f16(ah[i], bl[j], acc[i][j], 0, 0, 0);
    }
    __syncthreads();
  }
  const int crow = quad * 4, ccol = fr;
#pragma unroll
  for (int i = 0; i < 4; ++i)
#pragma unroll
    for (int j = 0; j < 4; ++j) {
      float v[4];
#pragma unroll
      for (int r = 0; r < 4; ++r) v[r] = acc[i][j][r] * 0.000244140625f;  // 2^-12
      const long gmb = m0 + mB + i * 16 + crow;
      const long gn = n0 + nB + j * 16 + ccol;
#pragma unroll
      for (int r = 0; r < 4; ++r) Cf[(gmb + r) * ldc + gn] = v[r];
      if (WT) {
        union { ushort4 u; f16_t h[4]; } ph, pl;
#pragma unroll
        for (int r = 0; r < 4; ++r) {
          f16_t h = (f16_t)v[r];
          ph.h[r] = h;
          pl.h[r] = (f16_t)(v[r] - (float)h);
        }
        *(ushort4*)(Th + gn * 2048 + gmb) = ph.u;
        *(ushort4*)(Tl + gn * 2048 + gmb) = pl.u;
      }
    }
}

// ------------- gate: one block per node n (grid 2048) ----------------------
__global__ __launch_bounds__(256) void gate_kernel(
    const float* __restrict__ x, const float* __restrict__ Xg1f,
    const float* __restrict__ Xg2r, const f16_t* __restrict__ Wg,
    const float* __restrict__ bpool, const float* __restrict__ emb,
    float* __restrict__ Zf, f16_t* __restrict__ rb) {
  __shared__ __align__(16) f16_t Ahi[32 * 200];
  __shared__ __align__(16) f16_t Alo[32 * 200];
  const int n = blockIdx.x;
  const int t = threadIdx.x;
  float en[10];
#pragma unroll
  for (int e = 0; e < 10; ++e) en[e] = emb[n * 10 + e];
  {
    const int b = t >> 3, i8 = (t & 7) * 8;
    const float* s0 = x + (long)b * 131072 + (long)n * 64 + i8;
    const float* s1 = Xg1f + (long)n * 2048 + b * 64 + i8;
    const float* s2 = Xg2r + (long)n * 2048 + b * 64 + i8;
    float v0[8], v1[8], v2[8];
#pragma unroll
    for (int j = 0; j < 8; ++j) v0[j] = s0[j];
#pragma unroll
    for (int j = 0; j < 8; ++j) v1[j] = s1[j];
#pragma unroll
    for (int j = 0; j < 8; ++j) v2[j] = 2.0f * s2[j] - v0[j];
    union { uint4 u; f16_t h[8]; } th, tl;
#pragma unroll
    for (int j = 0; j < 8; ++j) {
      f16_t h = (f16_t)v0[j]; th.h[j] = h; tl.h[j] = (f16_t)(v0[j] - (float)h);
    }
    *(uint4*)(Ahi + b * 200 + i8) = th.u;
    *(uint4*)(Alo + b * 200 + i8) = tl.u;
#pragma unroll
    for (int j = 0; j < 8; ++j) {
      f16_t h = (f16_t)v1[j]; th.h[j] = h; tl.h[j] = (f16_t)(v1[j] - (float)h);
    }
    *(uint4*)(Ahi + b * 200 + 64 + i8) = th.u;
    *(uint4*)(Alo + b * 200 + 64 + i8) = tl.u;
#pragma unroll
    for (int j = 0; j < 8; ++j) {
      f16_t h = (f16_t)v2[j]; th.h[j] = h; tl.h[j] = (f16_t)(v2[j] - (float)h);
    }
    *(uint4*)(Ahi + b * 200 + 128 + i8) = th.u;
    *(uint4*)(Alo + b * 200 + 128 + i8) = tl.u;
  }
  __syncthreads();
  const int wave = t >> 6, lane = t & 63;
  const int ob = wave * 32;
  const int fr = lane & 15, qk = (lane >> 4) * 8;
  const f16_t* Wp0 = Wg + (long)n * 24576 + (ob + fr) * 192 + qk;
  const f16_t* Wp1 = Wp0 + 16 * 192;
  f32x4 acc[2][2] = {};
#pragma unroll
  for (int k0 = 0; k0 < 192; k0 += 32) {
    f16x8 b0 = *(const f16x8*)(Wp0 + k0);
    f16x8 b1 = *(const f16x8*)(Wp1 + k0);
    f16x8 a0h = *(const f16x8*)(Ahi + fr * 200 + k0 + qk);
    f16x8 a1h = *(const f16x8*)(Ahi + (16 + fr) * 200 + k0 + qk);
    f16x8 a0l = *(const f16x8*)(Alo + fr * 200 + k0 + qk);
    f16x8 a1l = *(const f16x8*)(Alo + (16 + fr) * 200 + k0 + qk);
    acc[0][0] = __builtin_amdgcn_mfma_f32_16x16x32_f16(a0h, b0, acc[0][0], 0, 0, 0);
    acc[0][0] = __builtin_amdgcn_mfma_f32_16x16x32_f16(a0l, b0, acc[0][0], 0, 0, 0);
    acc[1][0] = __builtin_amdgcn_mfma_f32_16x16x32_f16(a1h, b0, acc[1][0], 0, 0, 0);
    acc[1][0] = __builtin_amdgcn_mfma_f32_16x16x32_f16(a1l, b0, acc[1][0], 0, 0, 0);
    acc[0][1] = __builtin_amdgcn_mfma_f32_16x16x32_f16(a0h, b1, acc[0][1], 0, 0, 0);
    acc[0][1] = __builtin_amdgcn_mfma_f32_16x16x32_f16(a0l, b1, acc[0][1], 0, 0, 0);
    acc[1][1] = __builtin_amdgcn_mfma_f32_16x16x32_f16(a1h, b1, acc[1][1], 0, 0, 0);
    acc[1][1] = __builtin_amdgcn_mfma_f32_16x16x32_f16(a1l, b1, acc[1][1], 0, 0, 0);
  }
  const int quad = lane >> 4;
#pragma unroll
  for (int j = 0; j < 2; ++j) {
    const int o = ob + j * 16 + fr;   // 0..127
    float bias = 0.f;
#pragma unroll
    for (int e = 0; e < 10; ++e) bias += en[e] * bpool[e * 128 + o];
#pragma unroll
    for (int i2 = 0; i2 < 2; ++i2)
#pragma unroll
      for (int r = 0; r < 4; ++r) {
        const int b = i2 * 16 + quad * 4 + r;
        float v = acc[i2][j][r] + bias;
        v = 1.0f / (1.0f + expf(-v));
        if (o < 64)
          Zf[(long)n * 2048 + b * 64 + o] = v;
        else
          rb[(long)n * 2048 + b * 64 + (o - 64)] = (f16_t)v;
      }
  }
}

// ------------- update: one block per node n (grid 2048) --------------------
__global__ __launch_bounds__(256) void update_kernel(
    const float* __restrict__ x, const float* __restrict__ Zf,
    const float* __restrict__ Xg1f, const float* __restrict__ Cgz1f,
    const float* __restrict__ Xg2r, const float* __restrict__ Cgz2r,
    const f16_t* __restrict__ Wu, const float* __restrict__ bpool,
    const float* __restrict__ emb, const f16_t* __restrict__ rb,
    float* __restrict__ out) {
  __shared__ __align__(16) f16_t Ahi[32 * 392];
  __shared__ __align__(16) f16_t Alo[32 * 392];
  const int n = blockIdx.x;
  const int t = threadIdx.x;
  float en[10];
#pragma unroll
  for (int e = 0; e < 10; ++e) en[e] = emb[n * 10 + e];
#pragma unroll
  for (int r = 0; r < 2; ++r) {
    const int c = r * 2048 + t * 8;  // (b, j) over 32 x 128
    const int b = c >> 7, j = c & 127;
    const int lo64 = j & 63;
    const float* s0 = (j < 64) ? (x + (long)b * 131072 + (long)n * 64 + lo64)
                               : (Zf + (long)n * 2048 + b * 64 + lo64);
    const float* s1 = (j < 64) ? (Xg1f + (long)n * 2048 + b * 64 + lo64)
                               : (Cgz1f + (long)n * 2048 + b * 64 + lo64);
    const float* s2 = (j < 64) ? (Xg2r + (long)n * 2048 + b * 64 + lo64)
                               : (Cgz2r + (long)n * 2048 + b * 64 + lo64);
    float v0[8], v1[8], v2[8];
#pragma unroll
    for (int q = 0; q < 8; ++q) v0[q] = s0[q];
#pragma unroll
    for (int q = 0; q < 8; ++q) v1[q] = s1[q];
#pragma unroll
    for (int q = 0; q < 8; ++q) v2[q] = 2.0f * s2[q] - v0[q];
    union { uint4 u; f16_t h[8]; } th, tl;
#pragma unroll
    for (int q = 0; q < 8; ++q) {
      f16_t h = (f16_t)v0[q]; th.h[q] = h; tl.h[q] = (f16_t)(v0[q] - (float)h);
    }
    *(uint4*)(Ahi + b * 392 + j) = th.u;
    *(uint4*)(Alo + b * 392 + j) = tl.u;
#pragma unroll
    for (int q = 0; q < 8; ++q) {
      f16_t h = (f16_t)v1[q]; th.h[q] = h; tl.h[q] = (f16_t)(v1[q] - (float)h);
    }
    *(uint4*)(Ahi + b * 392 + 128 + j) = th.u;
    *(uint4*)(Alo + b * 392 + 128 + j) = tl.u;
#pragma unroll
    for (int q = 0; q < 8; ++q) {
      f16_t h = (f16_t)v2[q]; th.h[q] = h; tl.h[q] = (f16_t)(v2[q] - (float)h);
    }
    *(uint4*)(Ahi + b * 392 + 256 + j) = th.u;
    *(uint4*)(Alo + b * 392 + 256 + j) = tl.u;
  }
  __syncthreads();
  const int wave = t >> 6, lane = t & 63;
  const int ob = wave * 16;            // 64 o across 4 waves
  const int fr = lane & 15, qk = (lane >> 4) * 8;
  const f16_t* Wp = Wu + (long)n * 24576 + (ob + fr) * 384 + qk;
  f32x4 acc[2] = {};
#pragma unroll
  for (int k0 = 0; k0 < 384; k0 += 32) {
    f16x8 bhv = *(const f16x8*)(Wp + k0);
    f16x8 a0h = *(const f16x8*)(Ahi + fr * 392 + k0 + qk);
    f16x8 a1h = *(const f16x8*)(Ahi + (16 + fr) * 392 + k0 + qk);
    f16x8 a0l = *(const f16x8*)(Alo + fr * 392 + k0 + qk);
    f16x8 a1l = *(const f16x8*)(Alo + (16 + fr) * 392 + k0 + qk);
    acc[0] = __builtin_amdgcn_mfma_f32_16x16x32_f16(a0h, bhv, acc[0], 0, 0, 0);
    acc[0] = __builtin_amdgcn_mfma_f32_16x16x32_f16(a0l, bhv, acc[0], 0, 0, 0);
    acc[1] = __builtin_amdgcn_mfma_f32_16x16x32_f16(a1h, bhv, acc[1], 0, 0, 0);
    acc[1] = __builtin_amdgcn_mfma_f32_16x16x32_f16(a1l, bhv, acc[1], 0, 0, 0);
  }
  const int quad = lane >> 4;
  const int og = ob + fr;
  float bias = 0.f;
#pragma unroll
  for (int e = 0; e < 10; ++e) bias += en[e] * bpool[e * 64 + og];
#pragma unroll
  for (int i2 = 0; i2 < 2; ++i2)
#pragma unroll
    for (int r = 0; r < 4; ++r) {
      const int b = i2 * 16 + quad * 4 + r;
      float hc = tanhf(acc[i2][r] + bias);
      float rr = (float)rb[(long)n * 2048 + b * 64 + og];
      float xv = x[(long)b * 131072 + (long)n * 64 + og];
      out[(long)b * 131072 + (long)n * 64 + og] = rr * xv + (1.0f - rr) * hc;
    }
}

extern "C" void kernel_launch(void* const* d_in, const int* in_sizes, int n_in,
                              void* d_out, int out_size, void* d_ws, size_t ws_size,
                              hipStream_t stream) {
  (void)in_sizes; (void)n_in; (void)out_size;
  const float* x   = (const float*)d_in[0];
  const float* emb = (const float*)d_in[2];
  const float* gwp = (const float*)d_in[3];
  const float* gbp = (const float*)d_in[4];
  const float* uwp = (const float*)d_in[5];
  const float* ubp = (const float*)d_in[6];
  float* out = (float*)d_out;
  char* ws = (char*)d_ws;

  // high-water 194,904,064 B (unchanged from prior round). Guard:
  if (ws_size < 194904064ull) return;

  // ---- live-range-checked layout (fp16 everywhere; W buffers 96 MiB) ----
  // Phases: P0 setup | P1 G1,G2 | P2 gate | P3 tsplit,G3,G4 | P4 wgen(Wu),update
  float*  Xg1f  = (float*)(ws);                  // 16 MiB   (live P1..P4)
  float*  Xg2r  = (float*)(ws + 16777216);       // 16 MiB   (live P1..P4)
  float*  Zf    = (float*)(ws + 33554432);       // 16 MiB   (gate out, P2..P4)
  f16_t*  T1h   = (f16_t*)(ws + 33554432);       //  8 MiB overlay (P1 only: G1->G2)
  f16_t*  T1l   = (f16_t*)(ws + 41943040);       //  8 MiB overlay (P1 only)
  f16_t*  rb    = (f16_t*)(ws + 50331648);       //  8 MiB   (P2..P4)
  float*  Pg    = (float*)(ws + 58720256);       // 983040
  float*  Pu    = (float*)(ws + 59703296);       // 983040
  f16_t*  adjF  = (f16_t*)(ws + 60686336);       //  8 MiB   (P0..P3)
  f16_t*  Sh    = (f16_t*)(ws + 69074944);       //  8 MiB   (split_xt / tsplit out)
  f16_t*  Sl    = (f16_t*)(ws + 77463552);       //  8 MiB
  f16_t*  Wg    = (f16_t*)(ws + 85852160);       // 96 MiB, ends 186515456 (dead post-gate)
  f16_t*  T2h   = (f16_t*)(ws + 85852160);       //  8 MiB overlay Wg head (P3: G3->G4)
  f16_t*  T2l   = (f16_t*)(ws + 94240768);       //  8 MiB overlay (P3)
  f16_t*  Wu    = (f16_t*)(ws + 60686336);       // 96 MiB overlay adjF/S/T2/Wg-head (P4)
  float*  Cgz1f = (float*)(ws + 161349632);      // 16 MiB (old-Wg tail, P3..P4)
  float*  Cgz2r = (float*)(ws + 178126848);      // 16 MiB, ends exactly 194904064

  permute_pool<<<960, 256, 0, stream>>>(gwp, Pg, 192, 64, 128);
  permute_pool<<<960, 256, 0, stream>>>(uwp, Pu, 384, 128, 64);
  wgen<<<dim3(24, 128), 256, 0, stream>>>(Pg, emb, Wg);
  adj_softmax<<<2048, 256, 0, stream>>>(emb, adjF);
  split_xt<<<dim3(32, 32), 256, 0, stream>>>(x, Sh, Sl);

  // G1: Xg1 = adj @ X     (+ fused transposed split -> T1)
  fgemm<1><<<dim3(16, 16), 256, 0, stream>>>(adjF, Sh, Sl, Xg1f, T1h, T1l, 2048, 2048);
  // G2: Xg2 = adj @ Xg1
  fgemm<0><<<dim3(16, 16), 256, 0, stream>>>(adjF, T1h, T1l, Xg2r, nullptr, nullptr, 2048, 2048);

  gate_kernel<<<2048, 256, 0, stream>>>(x, Xg1f, Xg2r, Wg, gbp, emb, Zf, rb);

  tsplit<<<dim3(32, 32), 256, 0, stream>>>(Zf, Sh, Sl, 2048, 2048);
  // G3: Cgz1 = adj @ Z    (+ fused transposed split -> T2, in dead-Wg space)
  fgemm<1><<<dim3(16, 16), 256, 0, stream>>>(adjF, Sh, Sl, Cgz1f, T2h, T2l, 2048, 2048);
  // G4: Cgz2 = adj @ Cgz1
  fgemm<0><<<dim3(16, 16), 256, 0, stream>>>(adjF, T2h, T2l, Cgz2r, nullptr, nullptr, 2048, 2048);

  wgen<<<dim3(24, 128), 256, 0, stream>>>(Pu, emb, Wu);
  update_kernel<<<2048, 256, 0, stream>>>(x, Zf, Xg1f, Cgz1f, Xg2r, Cgz2r, Wu,
                                          ubp, emb, rb, out);
}

// Round 5
// 439.178 us; speedup vs baseline: 1.0438x; 1.0438x over previous
//
#include <hip/hip_runtime.h>

typedef _Float16 f16_t;
typedef float f32x4 __attribute__((ext_vector_type(4)));
typedef _Float16 f16x8 __attribute__((ext_vector_type(8)));

#define AS1 __attribute__((address_space(1)))
#define AS3 __attribute__((address_space(3)))

__device__ __forceinline__ void gload_lds16(const void* g, void* l) {
  __builtin_amdgcn_global_load_lds((const AS1 void*)g, (AS3 void*)l, 16, 0, 0);
}

// ------------- adj = softmax(relu(E E^T), axis=1), single fp16 plane -------
// Stored pre-scaled by 2^12 so tiny softmax entries stay out of the fp16
// denormal range; fgemm epilogue multiplies by 2^-12.
__global__ __launch_bounds__(256) void adj_softmax(const float* __restrict__ emb,
                                                   f16_t* __restrict__ adjF) {
  __shared__ float vals[2048];
  __shared__ float red[16];
  const int n = blockIdx.x;
  const int t = threadIdx.x;
  const int lane = t & 63, wave = t >> 6;
  float en[10];
#pragma unroll
  for (int e = 0; e < 10; ++e) en[e] = emb[n * 10 + e];
  float lm = 0.0f;
  for (int m = t; m < 2048; m += 256) {
    const float* em = emb + m * 10;
    float d = 0.f;
#pragma unroll
    for (int e = 0; e < 10; ++e) d += en[e] * em[e];
    d = fmaxf(d, 0.0f);
    vals[m] = d;
    lm = fmaxf(lm, d);
  }
#pragma unroll
  for (int off = 32; off > 0; off >>= 1) lm = fmaxf(lm, __shfl_down(lm, off));
  if (lane == 0) red[wave] = lm;
  __syncthreads();
  const float gmax = fmaxf(fmaxf(red[0], red[1]), fmaxf(red[2], red[3]));
  float ls = 0.f;
  for (int m = t; m < 2048; m += 256) {
    float ev = expf(vals[m] - gmax);
    vals[m] = ev;
    ls += ev;
  }
#pragma unroll
  for (int off = 32; off > 0; off >>= 1) ls += __shfl_down(ls, off);
  if (lane == 0) red[8 + wave] = ls;
  __syncthreads();
  const float inv = 4096.0f / (red[8] + red[9] + red[10] + red[11]);
  for (int m = t; m < 2048; m += 256) {
    adjF[(long)n * 2048 + m] = (f16_t)(vals[m] * inv);
  }
}

// ------------- XT[b*64+i][m] = x[b][m][i], fp16 hi/lo planes ---------------
__global__ __launch_bounds__(256) void split_xt(const float* __restrict__ x,
                                                f16_t* __restrict__ XTh,
                                                f16_t* __restrict__ XTl) {
  __shared__ float tile[64][65];
  const int m0 = blockIdx.x * 64;
  const int b = blockIdx.y;
  const int tx = threadIdx.x & 63, ty = threadIdx.x >> 6;
  for (int r = ty; r < 64; r += 4)
    tile[r][tx] = x[(long)b * 131072 + (long)(m0 + r) * 64 + tx];
  __syncthreads();
  for (int r = ty; r < 64; r += 4) {
    float v = tile[tx][r];
    f16_t h = (f16_t)v;
    long idx = (long)(b * 64 + r) * 2048 + m0 + tx;
    XTh[idx] = h;
    XTl[idx] = (f16_t)(v - (float)h);
  }
}

// ------------- generic fp32 transpose-split: out[c][r] = in[r][c] ----------
__global__ __launch_bounds__(256) void tsplit(const float* __restrict__ in,
                                              f16_t* __restrict__ oH,
                                              f16_t* __restrict__ oL, int R, int C) {
  __shared__ float tile[64][65];
  const int c0 = blockIdx.x * 64, r0 = blockIdx.y * 64;
  const int tx = threadIdx.x & 63, ty = threadIdx.x >> 6;
  for (int r = ty; r < 64; r += 4)
    tile[r][tx] = in[(long)(r0 + r) * C + c0 + tx];
  __syncthreads();
  for (int r = ty; r < 64; r += 4) {
    float v = tile[tx][r];
    f16_t h = (f16_t)v;
    long idx = (long)(c0 + r) * R + r0 + tx;
    oH[idx] = h;
    oL[idx] = (f16_t)(v - (float)h);
  }
}

// ------------- permute w_pool (E,3,I,O) -> P[e][o*KI + k*I+i], fp32 --------
__global__ __launch_bounds__(256) void permute_pool(const float* __restrict__ wp,
                                                    float* __restrict__ P,
                                                    int KI, int I, int O) {
  const int g = blockIdx.x * 256 + threadIdx.x;
  const int per = KI * O;  // 24576
  const int e = g / per, rem = g % per;
  const int o = rem / KI, kk = rem % KI;
  const int k = kk / I, i = kk % I;
  P[g] = wp[(long)((e * 3 + k) * I + i) * O + o];
}

// ------------- W[n][c] = fp16(sum_e emb[n,e] * P[e][c]) — 96 MiB out -------
__global__ __launch_bounds__(256) void wgen(const float* __restrict__ P,
                                            const float* __restrict__ emb,
                                            f16_t* __restrict__ W) {
  __shared__ float Ps[10 * 1024];
  __shared__ float es[160];
  const int c0 = blockIdx.x * 1024;
  const int n0 = blockIdx.y * 16;
  const int t = threadIdx.x;
  for (int g = t; g < 10240; g += 256) {
    int e = g >> 10, idx = g & 1023;
    Ps[g] = P[(long)e * 24576 + c0 + idx];
  }
  if (t < 160) es[t] = emb[n0 * 10 + t];
  __syncthreads();
  for (int nn = 0; nn < 16; ++nn) {
    float e0 = es[nn * 10 + 0], e1 = es[nn * 10 + 1], e2 = es[nn * 10 + 2],
          e3 = es[nn * 10 + 3], e4 = es[nn * 10 + 4], e5 = es[nn * 10 + 5],
          e6 = es[nn * 10 + 6], e7 = es[nn * 10 + 7], e8 = es[nn * 10 + 8],
          e9 = es[nn * 10 + 9];
#pragma unroll
    for (int q = 0; q < 4; ++q) {
      int idx = q * 256 + t;
      float v = e0 * Ps[idx] + e1 * Ps[1024 + idx] + e2 * Ps[2048 + idx] +
                e3 * Ps[3072 + idx] + e4 * Ps[4096 + idx] + e5 * Ps[5120 + idx] +
                e6 * Ps[6144 + idx] + e7 * Ps[7168 + idx] + e8 * Ps[8192 + idx] +
                e9 * Ps[9216 + idx];
      W[(long)(n0 + nn) * 24576 + c0 + idx] = (f16_t)v;
    }
  }
}

// ------------- unified fused GEMM (fp16) v5 --------------------------------
// R1-proven structure (128Mx64N block, 4 waves of 32Mx64N, BK=64, single-
// buffered 2-barrier loop, 2 blocks/CU) with ONE change: the A operand skips
// LDS entirely.  Each A granule (16B along K) is consumed by exactly one
// lane of one wave, so LDS staging for A was a pure round-trip; direct
// global->VGPR loads issue the IDENTICAL 16B granule set (same L2/HBM
// traffic) while cutting per-block-step LDS traffic 112KB -> 80KB and LDS
// footprint 32KB -> 16KB.  B (hi/lo planes) keeps the XOR-swizzled LDS path.
// A = adj single fp16 plane (pre-scaled 2^12); epilogue multiplies 2^-12.
// WT: also emit transposed hi/lo split of C (next GEMM's B operand).
template <int WT>
__global__ __launch_bounds__(256) void fgemm(const f16_t* __restrict__ A,
                                             const f16_t* __restrict__ Bh,
                                             const f16_t* __restrict__ Bl,
                                             float* __restrict__ Cf,
                                             f16_t* __restrict__ Th,
                                             f16_t* __restrict__ Tl,
                                             int K, int ldc) {
  __shared__ __align__(16) f16_t Bsh[64 * 64];
  __shared__ __align__(16) f16_t Bsl[64 * 64];
  const int t = threadIdx.x;
  const int wave = t >> 6, lane = t & 63;
  const long m0 = (long)blockIdx.y * 128;
  const long n0 = (long)blockIdx.x * 64;
  const int srow = t >> 3;                       // 0..31
  const int sc8 = ((t & 7) ^ (srow & 7)) << 3;   // pre-swizzled source granule
  const int fr = lane & 15;
  const int quad = lane >> 4;
  const int wm = wave * 32;
  // Per-lane A row pointers (k-offset quad*8 within each 32-wide kh chunk).
  const f16_t* a0p = A + (m0 + wm + fr) * (long)K + quad * 8;
  const f16_t* a1p = A + (m0 + wm + 16 + fr) * (long)K + quad * 8;
  char* lB = (char*)Bsh + wave * 1024;
  char* lC = (char*)Bsl + wave * 1024;
  f32x4 acc[2][4] = {};
  for (int k0 = 0; k0 < K; k0 += 64) {
#pragma unroll
    for (int q = 0; q < 2; ++q)
      gload_lds16(Bh + (n0 + q * 32 + srow) * K + k0 + sc8, lB + q * 4096);
#pragma unroll
    for (int q = 0; q < 2; ++q)
      gload_lds16(Bl + (n0 + q * 32 + srow) * K + k0 + sc8, lC + q * 4096);
    // A fragments for this K-step: global -> VGPR (no LDS round trip).
    f16x8 af[2][2];  // [i][kh]
#pragma unroll
    for (int kh = 0; kh < 2; ++kh) {
      af[0][kh] = *(const f16x8*)(a0p + k0 + kh * 32);
      af[1][kh] = *(const f16x8*)(a1p + k0 + kh * 32);
    }
    __syncthreads();   // drains gload_lds (vmcnt0) AND the A loads
#pragma unroll
    for (int kh = 0; kh < 2; ++kh) {
      const int cbase = kh * 4 + quad;
      const int so = ((cbase ^ (fr & 7)) << 3);
      f16x8 bh[4], bl[4];
#pragma unroll
      for (int j = 0; j < 4; ++j) {
        const int r = j * 16 + fr;
        bh[j] = *(const f16x8*)(Bsh + r * 64 + so);
        bl[j] = *(const f16x8*)(Bsl + r * 64 + so);
      }
#pragma unroll
      for (int i = 0; i < 2; ++i)
#pragma unroll
        for (int j = 0; j < 4; ++j)
          acc[i][j] = __builtin_amdgcn_mfma_f32_16x16x32_f16(af[i][kh], bh[j], acc[i][j], 0, 0, 0);
#pragma unroll
      for (int i = 0; i < 2; ++i)
#pragma unroll
        for (int j = 0; j < 4; ++j)
          acc[i][j] = __builtin_amdgcn_mfma_f32_16x16x32_f16(af[i][kh], bl[j], acc[i][j], 0, 0, 0);
    }
    __syncthreads();
  }
  const int crow = quad * 4, ccol = fr;
#pragma unroll
  for (int i = 0; i < 2; ++i)
#pragma unroll
    for (int j = 0; j < 4; ++j) {
      float v[4];
#pragma unroll
      for (int r = 0; r < 4; ++r) v[r] = acc[i][j][r] * 0.000244140625f;  // 2^-12
      const long gmb = m0 + wm + i * 16 + crow;
      const long gn = n0 + j * 16 + ccol;
#pragma unroll
      for (int r = 0; r < 4; ++r) Cf[(gmb + r) * ldc + gn] = v[r];
      if (WT) {
        union { ushort4 u; f16_t h[4]; } ph, pl;
#pragma unroll
        for (int r = 0; r < 4; ++r) {
          f16_t h = (f16_t)v[r];
          ph.h[r] = h;
          pl.h[r] = (f16_t)(v[r] - (float)h);
        }
        *(ushort4*)(Th + gn * 2048 + gmb) = ph.u;
        *(ushort4*)(Tl + gn * 2048 + gmb) = pl.u;
      }
    }
}

// ------------- gate: one block per node n (grid 2048) ----------------------
__global__ __launch_bounds__(256) void gate_kernel(
    const float* __restrict__ x, const float* __restrict__ Xg1f,
    const float* __restrict__ Xg2r, const f16_t* __restrict__ Wg,
    const float* __restrict__ bpool, const float* __restrict__ emb,
    float* __restrict__ Zf, f16_t* __restrict__ rb) {
  __shared__ __align__(16) f16_t Ahi[32 * 200];
  __shared__ __align__(16) f16_t Alo[32 * 200];
  const int n = blockIdx.x;
  const int t = threadIdx.x;
  float en[10];
#pragma unroll
  for (int e = 0; e < 10; ++e) en[e] = emb[n * 10 + e];
  {
    const int b = t >> 3, i8 = (t & 7) * 8;
    const float* s0 = x + (long)b * 131072 + (long)n * 64 + i8;
    const float* s1 = Xg1f + (long)n * 2048 + b * 64 + i8;
    const float* s2 = Xg2r + (long)n * 2048 + b * 64 + i8;
    float v0[8], v1[8], v2[8];
#pragma unroll
    for (int j = 0; j < 8; ++j) v0[j] = s0[j];
#pragma unroll
    for (int j = 0; j < 8; ++j) v1[j] = s1[j];
#pragma unroll
    for (int j = 0; j < 8; ++j) v2[j] = 2.0f * s2[j] - v0[j];
    union { uint4 u; f16_t h[8]; } th, tl;
#pragma unroll
    for (int j = 0; j < 8; ++j) {
      f16_t h = (f16_t)v0[j]; th.h[j] = h; tl.h[j] = (f16_t)(v0[j] - (float)h);
    }
    *(uint4*)(Ahi + b * 200 + i8) = th.u;
    *(uint4*)(Alo + b * 200 + i8) = tl.u;
#pragma unroll
    for (int j = 0; j < 8; ++j) {
      f16_t h = (f16_t)v1[j]; th.h[j] = h; tl.h[j] = (f16_t)(v1[j] - (float)h);
    }
    *(uint4*)(Ahi + b * 200 + 64 + i8) = th.u;
    *(uint4*)(Alo + b * 200 + 64 + i8) = tl.u;
#pragma unroll
    for (int j = 0; j < 8; ++j) {
      f16_t h = (f16_t)v2[j]; th.h[j] = h; tl.h[j] = (f16_t)(v2[j] - (float)h);
    }
    *(uint4*)(Ahi + b * 200 + 128 + i8) = th.u;
    *(uint4*)(Alo + b * 200 + 128 + i8) = tl.u;
  }
  __syncthreads();
  const int wave = t >> 6, lane = t & 63;
  const int ob = wave * 32;
  const int fr = lane & 15, qk = (lane >> 4) * 8;
  const f16_t* Wp0 = Wg + (long)n * 24576 + (ob + fr) * 192 + qk;
  const f16_t* Wp1 = Wp0 + 16 * 192;
  f32x4 acc[2][2] = {};
#pragma unroll
  for (int k0 = 0; k0 < 192; k0 += 32) {
    f16x8 b0 = *(const f16x8*)(Wp0 + k0);
    f16x8 b1 = *(const f16x8*)(Wp1 + k0);
    f16x8 a0h = *(const f16x8*)(Ahi + fr * 200 + k0 + qk);
    f16x8 a1h = *(const f16x8*)(Ahi + (16 + fr) * 200 + k0 + qk);
    f16x8 a0l = *(const f16x8*)(Alo + fr * 200 + k0 + qk);
    f16x8 a1l = *(const f16x8*)(Alo + (16 + fr) * 200 + k0 + qk);
    acc[0][0] = __builtin_amdgcn_mfma_f32_16x16x32_f16(a0h, b0, acc[0][0], 0, 0, 0);
    acc[0][0] = __builtin_amdgcn_mfma_f32_16x16x32_f16(a0l, b0, acc[0][0], 0, 0, 0);
    acc[1][0] = __builtin_amdgcn_mfma_f32_16x16x32_f16(a1h, b0, acc[1][0], 0, 0, 0);
    acc[1][0] = __builtin_amdgcn_mfma_f32_16x16x32_f16(a1l, b0, acc[1][0], 0, 0, 0);
    acc[0][1] = __builtin_amdgcn_mfma_f32_16x16x32_f16(a0h, b1, acc[0][1], 0, 0, 0);
    acc[0][1] = __builtin_amdgcn_mfma_f32_16x16x32_f16(a0l, b1, acc[0][1], 0, 0, 0);
    acc[1][1] = __builtin_amdgcn_mfma_f32_16x16x32_f16(a1h, b1, acc[1][1], 0, 0, 0);
    acc[1][1] = __builtin_amdgcn_mfma_f32_16x16x32_f16(a1l, b1, acc[1][1], 0, 0, 0);
  }
  const int quad = lane >> 4;
#pragma unroll
  for (int j = 0; j < 2; ++j) {
    const int o = ob + j * 16 + fr;   // 0..127
    float bias = 0.f;
#pragma unroll
    for (int e = 0; e < 10; ++e) bias += en[e] * bpool[e * 128 + o];
#pragma unroll
    for (int i2 = 0; i2 < 2; ++i2)
#pragma unroll
      for (int r = 0; r < 4; ++r) {
        const int b = i2 * 16 + quad * 4 + r;
        float v = acc[i2][j][r] + bias;
        v = 1.0f / (1.0f + expf(-v));
        if (o < 64)
          Zf[(long)n * 2048 + b * 64 + o] = v;
        else
          rb[(long)n * 2048 + b * 64 + (o - 64)] = (f16_t)v;
      }
  }
}

// ------------- update: one block per node n (grid 2048) --------------------
__global__ __launch_bounds__(256) void update_kernel(
    const float* __restrict__ x, const float* __restrict__ Zf,
    const float* __restrict__ Xg1f, const float* __restrict__ Cgz1f,
    const float* __restrict__ Xg2r, const float* __restrict__ Cgz2r,
    const f16_t* __restrict__ Wu, const float* __restrict__ bpool,
    const float* __restrict__ emb, const f16_t* __restrict__ rb,
    float* __restrict__ out) {
  __shared__ __align__(16) f16_t Ahi[32 * 392];
  __shared__ __align__(16) f16_t Alo[32 * 392];
  const int n = blockIdx.x;
  const int t = threadIdx.x;
  float en[10];
#pragma unroll
  for (int e = 0; e < 10; ++e) en[e] = emb[n * 10 + e];
#pragma unroll
  for (int r = 0; r < 2; ++r) {
    const int c = r * 2048 + t * 8;  // (b, j) over 32 x 128
    const int b = c >> 7, j = c & 127;
    const int lo64 = j & 63;
    const float* s0 = (j < 64) ? (x + (long)b * 131072 + (long)n * 64 + lo64)
                               : (Zf + (long)n * 2048 + b * 64 + lo64);
    const float* s1 = (j < 64) ? (Xg1f + (long)n * 2048 + b * 64 + lo64)
                               : (Cgz1f + (long)n * 2048 + b * 64 + lo64);
    const float* s2 = (j < 64) ? (Xg2r + (long)n * 2048 + b * 64 + lo64)
                               : (Cgz2r + (long)n * 2048 + b * 64 + lo64);
    float v0[8], v1[8], v2[8];
#pragma unroll
    for (int q = 0; q < 8; ++q) v0[q] = s0[q];
#pragma unroll
    for (int q = 0; q < 8; ++q) v1[q] = s1[q];
#pragma unroll
    for (int q = 0; q < 8; ++q) v2[q] = 2.0f * s2[q] - v0[q];
    union { uint4 u; f16_t h[8]; } th, tl;
#pragma unroll
    for (int q = 0; q < 8; ++q) {
      f16_t h = (f16_t)v0[q]; th.h[q] = h; tl.h[q] = (f16_t)(v0[q] - (float)h);
    }
    *(uint4*)(Ahi + b * 392 + j) = th.u;
    *(uint4*)(Alo + b * 392 + j) = tl.u;
#pragma unroll
    for (int q = 0; q < 8; ++q) {
      f16_t h = (f16_t)v1[q]; th.h[q] = h; tl.h[q] = (f16_t)(v1[q] - (float)h);
    }
    *(uint4*)(Ahi + b * 392 + 128 + j) = th.u;
    *(uint4*)(Alo + b * 392 + 128 + j) = tl.u;
#pragma unroll
    for (int q = 0; q < 8; ++q) {
      f16_t h = (f16_t)v2[q]; th.h[q] = h; tl.h[q] = (f16_t)(v2[q] - (float)h);
    }
    *(uint4*)(Ahi + b * 392 + 256 + j) = th.u;
    *(uint4*)(Alo + b * 392 + 256 + j) = tl.u;
  }
  __syncthreads();
  const int wave = t >> 6, lane = t & 63;
  const int ob = wave * 16;            // 64 o across 4 waves
  const int fr = lane & 15, qk = (lane >> 4) * 8;
  const f16_t* Wp = Wu + (long)n * 24576 + (ob + fr) * 384 + qk;
  f32x4 acc[2] = {};
#pragma unroll
  for (int k0 = 0; k0 < 384; k0 += 32) {
    f16x8 bhv = *(const f16x8*)(Wp + k0);
    f16x8 a0h = *(const f16x8*)(Ahi + fr * 392 + k0 + qk);
    f16x8 a1h = *(const f16x8*)(Ahi + (16 + fr) * 392 + k0 + qk);
    f16x8 a0l = *(const f16x8*)(Alo + fr * 392 + k0 + qk);
    f16x8 a1l = *(const f16x8*)(Alo + (16 + fr) * 392 + k0 + qk);
    acc[0] = __builtin_amdgcn_mfma_f32_16x16x32_f16(a0h, bhv, acc[0], 0, 0, 0);
    acc[0] = __builtin_amdgcn_mfma_f32_16x16x32_f16(a0l, bhv, acc[0], 0, 0, 0);
    acc[1] = __builtin_amdgcn_mfma_f32_16x16x32_f16(a1h, bhv, acc[1], 0, 0, 0);
    acc[1] = __builtin_amdgcn_mfma_f32_16x16x32_f16(a1l, bhv, acc[1], 0, 0, 0);
  }
  const int quad = lane >> 4;
  const int og = ob + fr;
  float bias = 0.f;
#pragma unroll
  for (int e = 0; e < 10; ++e) bias += en[e] * bpool[e * 64 + og];
#pragma unroll
  for (int i2 = 0; i2 < 2; ++i2)
#pragma unroll
    for (int r = 0; r < 4; ++r) {
      const int b = i2 * 16 + quad * 4 + r;
      float hc = tanhf(acc[i2][r] + bias);
      float rr = (float)rb[(long)n * 2048 + b * 64 + og];
      float xv = x[(long)b * 131072 + (long)n * 64 + og];
      out[(long)b * 131072 + (long)n * 64 + og] = rr * xv + (1.0f - rr) * hc;
    }
}

extern "C" void kernel_launch(void* const* d_in, const int* in_sizes, int n_in,
                              void* d_out, int out_size, void* d_ws, size_t ws_size,
                              hipStream_t stream) {
  (void)in_sizes; (void)n_in; (void)out_size;
  const float* x   = (const float*)d_in[0];
  const float* emb = (const float*)d_in[2];
  const float* gwp = (const float*)d_in[3];
  const float* gbp = (const float*)d_in[4];
  const float* uwp = (const float*)d_in[5];
  const float* ubp = (const float*)d_in[6];
  float* out = (float*)d_out;
  char* ws = (char*)d_ws;

  // high-water 194,904,064 B (unchanged from prior round). Guard:
  if (ws_size < 194904064ull) return;

  // ---- live-range-checked layout (fp16 everywhere; W buffers 96 MiB) ----
  // Phases: P0 setup | P1 G1,G2 | P2 gate | P3 tsplit,G3,G4 | P4 wgen(Wu),update
  float*  Xg1f  = (float*)(ws);                  // 16 MiB   (live P1..P4)
  float*  Xg2r  = (float*)(ws + 16777216);       // 16 MiB   (live P1..P4)
  float*  Zf    = (float*)(ws + 33554432);       // 16 MiB   (gate out, P2..P4)
  f16_t*  T1h   = (f16_t*)(ws + 33554432);       //  8 MiB overlay (P1 only: G1->G2)
  f16_t*  T1l   = (f16_t*)(ws + 41943040);       //  8 MiB overlay (P1 only)
  f16_t*  rb    = (f16_t*)(ws + 50331648);       //  8 MiB   (P2..P4)
  float*  Pg    = (float*)(ws + 58720256);       // 983040
  float*  Pu    = (float*)(ws + 59703296);       // 983040
  f16_t*  adjF  = (f16_t*)(ws + 60686336);       //  8 MiB   (P0..P3)
  f16_t*  Sh    = (f16_t*)(ws + 69074944);       //  8 MiB   (split_xt / tsplit out)
  f16_t*  Sl    = (f16_t*)(ws + 77463552);       //  8 MiB
  f16_t*  Wg    = (f16_t*)(ws + 85852160);       // 96 MiB, ends 186515456 (dead post-gate)
  f16_t*  T2h   = (f16_t*)(ws + 85852160);       //  8 MiB overlay Wg head (P3: G3->G4)
  f16_t*  T2l   = (f16_t*)(ws + 94240768);       //  8 MiB overlay (P3)
  f16_t*  Wu    = (f16_t*)(ws + 60686336);       // 96 MiB overlay adjF/S/T2/Wg-head (P4)
  float*  Cgz1f = (float*)(ws + 161349632);      // 16 MiB (old-Wg tail, P3..P4)
  float*  Cgz2r = (float*)(ws + 178126848);      // 16 MiB, ends exactly 194904064

  permute_pool<<<960, 256, 0, stream>>>(gwp, Pg, 192, 64, 128);
  permute_pool<<<960, 256, 0, stream>>>(uwp, Pu, 384, 128, 64);
  wgen<<<dim3(24, 128), 256, 0, stream>>>(Pg, emb, Wg);
  adj_softmax<<<2048, 256, 0, stream>>>(emb, adjF);
  split_xt<<<dim3(32, 32), 256, 0, stream>>>(x, Sh, Sl);

  // G1: Xg1 = adj @ X     (+ fused transposed split -> T1)
  fgemm<1><<<dim3(32, 16), 256, 0, stream>>>(adjF, Sh, Sl, Xg1f, T1h, T1l, 2048, 2048);
  // G2: Xg2 = adj @ Xg1
  fgemm<0><<<dim3(32, 16), 256, 0, stream>>>(adjF, T1h, T1l, Xg2r, nullptr, nullptr, 2048, 2048);

  gate_kernel<<<2048, 256, 0, stream>>>(x, Xg1f, Xg2r, Wg, gbp, emb, Zf, rb);

  tsplit<<<dim3(32, 32), 256, 0, stream>>>(Zf, Sh, Sl, 2048, 2048);
  // G3: Cgz1 = adj @ Z    (+ fused transposed split -> T2, in dead-Wg space)
  fgemm<1><<<dim3(32, 16), 256, 0, stream>>>(adjF, Sh, Sl, Cgz1f, T2h, T2l, 2048, 2048);
  // G4: Cgz2 = adj @ Cgz1
  fgemm<0><<<dim3(32, 16), 256, 0, stream>>>(adjF, T2h, T2l, Cgz2r, nullptr, nullptr, 2048, 2048);

  wgen<<<dim3(24, 128), 256, 0, stream>>>(Pu, emb, Wu);
  update_kernel<<<2048, 256, 0, stream>>>(x, Zf, Xg1f, Cgz1f, Xg2r, Cgz2r, Wu,
                                          ubp, emb, rb, out);
}

// Round 6
// 421.835 us; speedup vs baseline: 1.0867x; 1.0411x over previous
//
#include <hip/hip_runtime.h>

typedef _Float16 f16_t;
typedef float f32x4 __attribute__((ext_vector_type(4)));
typedef _Float16 f16x8 __attribute__((ext_vector_type(8)));

#define AS1 __attribute__((address_space(1)))
#define AS3 __attribute__((address_space(3)))

__device__ __forceinline__ void gload_lds16(const void* g, void* l) {
  __builtin_amdgcn_global_load_lds((const AS1 void*)g, (AS3 void*)l, 16, 0, 0);
}

// ------------- adj = softmax(relu(E E^T), axis=1), single fp16 plane -------
// Stored pre-scaled by 2^12 so tiny softmax entries stay out of the fp16
// denormal range; fgemm epilogue multiplies by 2^-12.
__global__ __launch_bounds__(256) void adj_softmax(const float* __restrict__ emb,
                                                   f16_t* __restrict__ adjF) {
  __shared__ float vals[2048];
  __shared__ float red[16];
  const int n = blockIdx.x;
  const int t = threadIdx.x;
  const int lane = t & 63, wave = t >> 6;
  float en[10];
#pragma unroll
  for (int e = 0; e < 10; ++e) en[e] = emb[n * 10 + e];
  float lm = 0.0f;
  for (int m = t; m < 2048; m += 256) {
    const float* em = emb + m * 10;
    float d = 0.f;
#pragma unroll
    for (int e = 0; e < 10; ++e) d += en[e] * em[e];
    d = fmaxf(d, 0.0f);
    vals[m] = d;
    lm = fmaxf(lm, d);
  }
#pragma unroll
  for (int off = 32; off > 0; off >>= 1) lm = fmaxf(lm, __shfl_down(lm, off));
  if (lane == 0) red[wave] = lm;
  __syncthreads();
  const float gmax = fmaxf(fmaxf(red[0], red[1]), fmaxf(red[2], red[3]));
  float ls = 0.f;
  for (int m = t; m < 2048; m += 256) {
    float ev = expf(vals[m] - gmax);
    vals[m] = ev;
    ls += ev;
  }
#pragma unroll
  for (int off = 32; off > 0; off >>= 1) ls += __shfl_down(ls, off);
  if (lane == 0) red[8 + wave] = ls;
  __syncthreads();
  const float inv = 4096.0f / (red[8] + red[9] + red[10] + red[11]);
  for (int m = t; m < 2048; m += 256) {
    adjF[(long)n * 2048 + m] = (f16_t)(vals[m] * inv);
  }
}

// ------------- XT[b*64+i][m] = x[b][m][i], fp16 hi/lo planes ---------------
__global__ __launch_bounds__(256) void split_xt(const float* __restrict__ x,
                                                f16_t* __restrict__ XTh,
                                                f16_t* __restrict__ XTl) {
  __shared__ float tile[64][65];
  const int m0 = blockIdx.x * 64;
  const int b = blockIdx.y;
  const int tx = threadIdx.x & 63, ty = threadIdx.x >> 6;
  for (int r = ty; r < 64; r += 4)
    tile[r][tx] = x[(long)b * 131072 + (long)(m0 + r) * 64 + tx];
  __syncthreads();
  for (int r = ty; r < 64; r += 4) {
    float v = tile[tx][r];
    f16_t h = (f16_t)v;
    long idx = (long)(b * 64 + r) * 2048 + m0 + tx;
    XTh[idx] = h;
    XTl[idx] = (f16_t)(v - (float)h);
  }
}

// ------------- generic fp32 transpose-split: out[c][r] = in[r][c] ----------
__global__ __launch_bounds__(256) void tsplit(const float* __restrict__ in,
                                              f16_t* __restrict__ oH,
                                              f16_t* __restrict__ oL, int R, int C) {
  __shared__ float tile[64][65];
  const int c0 = blockIdx.x * 64, r0 = blockIdx.y * 64;
  const int tx = threadIdx.x & 63, ty = threadIdx.x >> 6;
  for (int r = ty; r < 64; r += 4)
    tile[r][tx] = in[(long)(r0 + r) * C + c0 + tx];
  __syncthreads();
  for (int r = ty; r < 64; r += 4) {
    float v = tile[tx][r];
    f16_t h = (f16_t)v;
    long idx = (long)(c0 + r) * R + r0 + tx;
    oH[idx] = h;
    oL[idx] = (f16_t)(v - (float)h);
  }
}

// ------------- permute w_pool (E,3,I,O) -> P[e][o*KI + k*I+i], fp32 --------
__global__ __launch_bounds__(256) void permute_pool(const float* __restrict__ wp,
                                                    float* __restrict__ P,
                                                    int KI, int I, int O) {
  const int g = blockIdx.x * 256 + threadIdx.x;
  const int per = KI * O;  // 24576
  const int e = g / per, rem = g % per;
  const int o = rem / KI, kk = rem % KI;
  const int k = kk / I, i = kk % I;
  P[g] = wp[(long)((e * 3 + k) * I + i) * O + o];
}

// ------------- W[n][c] = fp16(sum_e emb[n,e] * P[e][c]) — 96 MiB out -------
// Round-6: vectorized (G13).  float4 LDS staging, P-slice hoisted to 10
// registers reused across all 16 nodes, ushort4 (8B) stores — replaces the
// previous 2B-scalar-store / 16x-LDS-reread version.
__global__ __launch_bounds__(256) void wgen(const float* __restrict__ P,
                                            const float* __restrict__ emb,
                                            f16_t* __restrict__ W) {
  __shared__ float es[160];
  const int c0 = blockIdx.x * 1024;
  const int n0 = blockIdx.y * 16;
  const int t = threadIdx.x;
  const int i4 = t * 4;
  if (t < 160) es[t] = emb[n0 * 10 + t];
  float4 p[10];
#pragma unroll
  for (int e = 0; e < 10; ++e)
    p[e] = *(const float4*)(P + (long)e * 24576 + c0 + i4);
  __syncthreads();
#pragma unroll 4
  for (int nn = 0; nn < 16; ++nn) {
    const float* ep = es + nn * 10;
    float v0 = 0.f, v1 = 0.f, v2 = 0.f, v3 = 0.f;
#pragma unroll
    for (int e = 0; e < 10; ++e) {
      const float ee = ep[e];
      v0 += ee * p[e].x; v1 += ee * p[e].y; v2 += ee * p[e].z; v3 += ee * p[e].w;
    }
    union { ushort4 u; f16_t h[4]; } o;
    o.h[0] = (f16_t)v0; o.h[1] = (f16_t)v1; o.h[2] = (f16_t)v2; o.h[3] = (f16_t)v3;
    *(ushort4*)(W + (long)(n0 + nn) * 24576 + c0 + i4) = o.u;
  }
}

// ------------- unified fused GEMM (fp16) — R1-proven structure -------------
// 128(M)x64(N) tile, BK=64, XOR-swizzled LDS, single-buffered 2-barrier
// K-loop, 2 blocks/CU.  Best measured: 48.2us/dispatch.  Rounds 2-5 tested
// dbuf / 64x32 retile+XCD-swizzle / 128x128 tile / A-in-VGPR — all null or
// negative; do not reintroduce without a structure-level (8-phase) rewrite.
// A = adj single fp16 plane (pre-scaled 2^12), B = fp16 hi/lo.
// WT: also emit transposed hi/lo split of C (next GEMM's B operand).
template <int WT>
__global__ __launch_bounds__(256) void fgemm(const f16_t* __restrict__ A,
                                             const f16_t* __restrict__ Bh,
                                             const f16_t* __restrict__ Bl,
                                             float* __restrict__ Cf,
                                             f16_t* __restrict__ Th,
                                             f16_t* __restrict__ Tl,
                                             int K, int ldc) {
  __shared__ __align__(16) f16_t Ash[128 * 64];
  __shared__ __align__(16) f16_t Bsh[64 * 64];
  __shared__ __align__(16) f16_t Bsl[64 * 64];
  const int t = threadIdx.x;
  const int wave = t >> 6, lane = t & 63;
  const long m0 = (long)blockIdx.y * 128;
  const long n0 = (long)blockIdx.x * 64;
  const int srow = t >> 3;
  const int sc8 = ((t & 7) ^ (srow & 7)) << 3;
  const int fr = lane & 15;
  const int quad = lane >> 4;
  const int wm = wave * 32;
  char* lA = (char*)Ash + wave * 1024;
  char* lB = (char*)Bsh + wave * 1024;
  char* lBl2 = (char*)Bsl + wave * 1024;
  f32x4 acc[2][4] = {};
  for (int k0 = 0; k0 < K; k0 += 64) {
#pragma unroll
    for (int q = 0; q < 4; ++q)
      gload_lds16(A + (m0 + q * 32 + srow) * K + k0 + sc8, lA + q * 4096);
#pragma unroll
    for (int q = 0; q < 2; ++q)
      gload_lds16(Bh + (n0 + q * 32 + srow) * K + k0 + sc8, lB + q * 4096);
#pragma unroll
    for (int q = 0; q < 2; ++q)
      gload_lds16(Bl + (n0 + q * 32 + srow) * K + k0 + sc8, lBl2 + q * 4096);
    __syncthreads();
#pragma unroll
    for (int kh = 0; kh < 2; ++kh) {
      const int cbase = kh * 4 + quad;
      f16x8 ah[2], bh[4], bl[4];
#pragma unroll
      for (int i = 0; i < 2; ++i) {
        const int r = wm + i * 16 + fr;
        ah[i] = *(const f16x8*)(Ash + r * 64 + ((cbase ^ (fr & 7)) << 3));
      }
#pragma unroll
      for (int j = 0; j < 4; ++j) {
        const int r = j * 16 + fr;
        bh[j] = *(const f16x8*)(Bsh + r * 64 + ((cbase ^ (fr & 7)) << 3));
        bl[j] = *(const f16x8*)(Bsl + r * 64 + ((cbase ^ (fr & 7)) << 3));
      }
#pragma unroll
      for (int i = 0; i < 2; ++i)
#pragma unroll
        for (int j = 0; j < 4; ++j)
          acc[i][j] = __builtin_amdgcn_mfma_f32_16x16x32_f16(ah[i], bh[j], acc[i][j], 0, 0, 0);
#pragma unroll
      for (int i = 0; i < 2; ++i)
#pragma unroll
        for (int j = 0; j < 4; ++j)
          acc[i][j] = __builtin_amdgcn_mfma_f32_16x16x32_f16(ah[i], bl[j], acc[i][j], 0, 0, 0);
    }
    __syncthreads();
  }
  const int crow = quad * 4, ccol = fr;
#pragma unroll
  for (int i = 0; i < 2; ++i)
#pragma unroll
    for (int j = 0; j < 4; ++j) {
      float v[4];
#pragma unroll
      for (int r = 0; r < 4; ++r) v[r] = acc[i][j][r] * 0.000244140625f;  // 2^-12
      const long gmb = m0 + wm + i * 16 + crow;
      const long gn = n0 + j * 16 + ccol;
#pragma unroll
      for (int r = 0; r < 4; ++r) Cf[(gmb + r) * ldc + gn] = v[r];
      if (WT) {
        union { ushort4 u; f16_t h[4]; } ph, pl;
#pragma unroll
        for (int r = 0; r < 4; ++r) {
          f16_t h = (f16_t)v[r];
          ph.h[r] = h;
          pl.h[r] = (f16_t)(v[r] - (float)h);
        }
        *(ushort4*)(Th + gn * 2048 + gmb) = ph.u;
        *(ushort4*)(Tl + gn * 2048 + gmb) = pl.u;
      }
    }
}

// ------------- gate: one block per node n (grid 2048) ----------------------
__global__ __launch_bounds__(256) void gate_kernel(
    const float* __restrict__ x, const float* __restrict__ Xg1f,
    const float* __restrict__ Xg2r, const f16_t* __restrict__ Wg,
    const float* __restrict__ bpool, const float* __restrict__ emb,
    float* __restrict__ Zf, f16_t* __restrict__ rb) {
  __shared__ __align__(16) f16_t Ahi[32 * 200];
  __shared__ __align__(16) f16_t Alo[32 * 200];
  const int n = blockIdx.x;
  const int t = threadIdx.x;
  float en[10];
#pragma unroll
  for (int e = 0; e < 10; ++e) en[e] = emb[n * 10 + e];
  {
    const int b = t >> 3, i8 = (t & 7) * 8;
    const float* s0 = x + (long)b * 131072 + (long)n * 64 + i8;
    const float* s1 = Xg1f + (long)n * 2048 + b * 64 + i8;
    const float* s2 = Xg2r + (long)n * 2048 + b * 64 + i8;
    float v0[8], v1[8], v2[8];
#pragma unroll
    for (int j = 0; j < 8; ++j) v0[j] = s0[j];
#pragma unroll
    for (int j = 0; j < 8; ++j) v1[j] = s1[j];
#pragma unroll
    for (int j = 0; j < 8; ++j) v2[j] = 2.0f * s2[j] - v0[j];
    union { uint4 u; f16_t h[8]; } th, tl;
#pragma unroll
    for (int j = 0; j < 8; ++j) {
      f16_t h = (f16_t)v0[j]; th.h[j] = h; tl.h[j] = (f16_t)(v0[j] - (float)h);
    }
    *(uint4*)(Ahi + b * 200 + i8) = th.u;
    *(uint4*)(Alo + b * 200 + i8) = tl.u;
#pragma unroll
    for (int j = 0; j < 8; ++j) {
      f16_t h = (f16_t)v1[j]; th.h[j] = h; tl.h[j] = (f16_t)(v1[j] - (float)h);
    }
    *(uint4*)(Ahi + b * 200 + 64 + i8) = th.u;
    *(uint4*)(Alo + b * 200 + 64 + i8) = tl.u;
#pragma unroll
    for (int j = 0; j < 8; ++j) {
      f16_t h = (f16_t)v2[j]; th.h[j] = h; tl.h[j] = (f16_t)(v2[j] - (float)h);
    }
    *(uint4*)(Ahi + b * 200 + 128 + i8) = th.u;
    *(uint4*)(Alo + b * 200 + 128 + i8) = tl.u;
  }
  __syncthreads();
  const int wave = t >> 6, lane = t & 63;
  const int ob = wave * 32;
  const int fr = lane & 15, qk = (lane >> 4) * 8;
  const f16_t* Wp0 = Wg + (long)n * 24576 + (ob + fr) * 192 + qk;
  const f16_t* Wp1 = Wp0 + 16 * 192;
  f32x4 acc[2][2] = {};
#pragma unroll
  for (int k0 = 0; k0 < 192; k0 += 32) {
    f16x8 b0 = *(const f16x8*)(Wp0 + k0);
    f16x8 b1 = *(const f16x8*)(Wp1 + k0);
    f16x8 a0h = *(const f16x8*)(Ahi + fr * 200 + k0 + qk);
    f16x8 a1h = *(const f16x8*)(Ahi + (16 + fr) * 200 + k0 + qk);
    f16x8 a0l = *(const f16x8*)(Alo + fr * 200 + k0 + qk);
    f16x8 a1l = *(const f16x8*)(Alo + (16 + fr) * 200 + k0 + qk);
    acc[0][0] = __builtin_amdgcn_mfma_f32_16x16x32_f16(a0h, b0, acc[0][0], 0, 0, 0);
    acc[0][0] = __builtin_amdgcn_mfma_f32_16x16x32_f16(a0l, b0, acc[0][0], 0, 0, 0);
    acc[1][0] = __builtin_amdgcn_mfma_f32_16x16x32_f16(a1h, b0, acc[1][0], 0, 0, 0);
    acc[1][0] = __builtin_amdgcn_mfma_f32_16x16x32_f16(a1l, b0, acc[1][0], 0, 0, 0);
    acc[0][1] = __builtin_amdgcn_mfma_f32_16x16x32_f16(a0h, b1, acc[0][1], 0, 0, 0);
    acc[0][1] = __builtin_amdgcn_mfma_f32_16x16x32_f16(a0l, b1, acc[0][1], 0, 0, 0);
    acc[1][1] = __builtin_amdgcn_mfma_f32_16x16x32_f16(a1h, b1, acc[1][1], 0, 0, 0);
    acc[1][1] = __builtin_amdgcn_mfma_f32_16x16x32_f16(a1l, b1, acc[1][1], 0, 0, 0);
  }
  const int quad = lane >> 4;
#pragma unroll
  for (int j = 0; j < 2; ++j) {
    const int o = ob + j * 16 + fr;   // 0..127
    float bias = 0.f;
#pragma unroll
    for (int e = 0; e < 10; ++e) bias += en[e] * bpool[e * 128 + o];
#pragma unroll
    for (int i2 = 0; i2 < 2; ++i2)
#pragma unroll
      for (int r = 0; r < 4; ++r) {
        const int b = i2 * 16 + quad * 4 + r;
        float v = acc[i2][j][r] + bias;
        v = 1.0f / (1.0f + expf(-v));
        if (o < 64)
          Zf[(long)n * 2048 + b * 64 + o] = v;
        else
          rb[(long)n * 2048 + b * 64 + (o - 64)] = (f16_t)v;
      }
  }
}

// ------------- update: one block per node n (grid 2048) --------------------
__global__ __launch_bounds__(256) void update_kernel(
    const float* __restrict__ x, const float* __restrict__ Zf,
    const float* __restrict__ Xg1f, const float* __restrict__ Cgz1f,
    const float* __restrict__ Xg2r, const float* __restrict__ Cgz2r,
    const f16_t* __restrict__ Wu, const float* __restrict__ bpool,
    const float* __restrict__ emb, const f16_t* __restrict__ rb,
    float* __restrict__ out) {
  __shared__ __align__(16) f16_t Ahi[32 * 392];
  __shared__ __align__(16) f16_t Alo[32 * 392];
  const int n = blockIdx.x;
  const int t = threadIdx.x;
  float en[10];
#pragma unroll
  for (int e = 0; e < 10; ++e) en[e] = emb[n * 10 + e];
#pragma unroll
  for (int r = 0; r < 2; ++r) {
    const int c = r * 2048 + t * 8;  // (b, j) over 32 x 128
    const int b = c >> 7, j = c & 127;
    const int lo64 = j & 63;
    const float* s0 = (j < 64) ? (x + (long)b * 131072 + (long)n * 64 + lo64)
                               : (Zf + (long)n * 2048 + b * 64 + lo64);
    const float* s1 = (j < 64) ? (Xg1f + (long)n * 2048 + b * 64 + lo64)
                               : (Cgz1f + (long)n * 2048 + b * 64 + lo64);
    const float* s2 = (j < 64) ? (Xg2r + (long)n * 2048 + b * 64 + lo64)
                               : (Cgz2r + (long)n * 2048 + b * 64 + lo64);
    float v0[8], v1[8], v2[8];
#pragma unroll
    for (int q = 0; q < 8; ++q) v0[q] = s0[q];
#pragma unroll
    for (int q = 0; q < 8; ++q) v1[q] = s1[q];
#pragma unroll
    for (int q = 0; q < 8; ++q) v2[q] = 2.0f * s2[q] - v0[q];
    union { uint4 u; f16_t h[8]; } th, tl;
#pragma unroll
    for (int q = 0; q < 8; ++q) {
      f16_t h = (f16_t)v0[q]; th.h[q] = h; tl.h[q] = (f16_t)(v0[q] - (float)h);
    }
    *(uint4*)(Ahi + b * 392 + j) = th.u;
    *(uint4*)(Alo + b * 392 + j) = tl.u;
#pragma unroll
    for (int q = 0; q < 8; ++q) {
      f16_t h = (f16_t)v1[q]; th.h[q] = h; tl.h[q] = (f16_t)(v1[q] - (float)h);
    }
    *(uint4*)(Ahi + b * 392 + 128 + j) = th.u;
    *(uint4*)(Alo + b * 392 + 128 + j) = tl.u;
#pragma unroll
    for (int q = 0; q < 8; ++q) {
      f16_t h = (f16_t)v2[q]; th.h[q] = h; tl.h[q] = (f16_t)(v2[q] - (float)h);
    }
    *(uint4*)(Ahi + b * 392 + 256 + j) = th.u;
    *(uint4*)(Alo + b * 392 + 256 + j) = tl.u;
  }
  __syncthreads();
  const int wave = t >> 6, lane = t & 63;
  const int ob = wave * 16;            // 64 o across 4 waves
  const int fr = lane & 15, qk = (lane >> 4) * 8;
  const f16_t* Wp = Wu + (long)n * 24576 + (ob + fr) * 384 + qk;
  f32x4 acc[2] = {};
#pragma unroll
  for (int k0 = 0; k0 < 384; k0 += 32) {
    f16x8 bhv = *(const f16x8*)(Wp + k0);
    f16x8 a0h = *(const f16x8*)(Ahi + fr * 392 + k0 + qk);
    f16x8 a1h = *(const f16x8*)(Ahi + (16 + fr) * 392 + k0 + qk);
    f16x8 a0l = *(const f16x8*)(Alo + fr * 392 + k0 + qk);
    f16x8 a1l = *(const f16x8*)(Alo + (16 + fr) * 392 + k0 + qk);
    acc[0] = __builtin_amdgcn_mfma_f32_16x16x32_f16(a0h, bhv, acc[0], 0, 0, 0);
    acc[0] = __builtin_amdgcn_mfma_f32_16x16x32_f16(a0l, bhv, acc[0], 0, 0, 0);
    acc[1] = __builtin_amdgcn_mfma_f32_16x16x32_f16(a1h, bhv, acc[1], 0, 0, 0);
    acc[1] = __builtin_amdgcn_mfma_f32_16x16x32_f16(a1l, bhv, acc[1], 0, 0, 0);
  }
  const int quad = lane >> 4;
  const int og = ob + fr;
  float bias = 0.f;
#pragma unroll
  for (int e = 0; e < 10; ++e) bias += en[e] * bpool[e * 64 + og];
#pragma unroll
  for (int i2 = 0; i2 < 2; ++i2)
#pragma unroll
    for (int r = 0; r < 4; ++r) {
      const int b = i2 * 16 + quad * 4 + r;
      float hc = tanhf(acc[i2][r] + bias);
      float rr = (float)rb[(long)n * 2048 + b * 64 + og];
      float xv = x[(long)b * 131072 + (long)n * 64 + og];
      out[(long)b * 131072 + (long)n * 64 + og] = rr * xv + (1.0f - rr) * hc;
    }
}

extern "C" void kernel_launch(void* const* d_in, const int* in_sizes, int n_in,
                              void* d_out, int out_size, void* d_ws, size_t ws_size,
                              hipStream_t stream) {
  (void)in_sizes; (void)n_in; (void)out_size;
  const float* x   = (const float*)d_in[0];
  const float* emb = (const float*)d_in[2];
  const float* gwp = (const float*)d_in[3];
  const float* gbp = (const float*)d_in[4];
  const float* uwp = (const float*)d_in[5];
  const float* ubp = (const float*)d_in[6];
  float* out = (float*)d_out;
  char* ws = (char*)d_ws;

  // high-water 194,904,064 B (unchanged from prior round). Guard:
  if (ws_size < 194904064ull) return;

  // ---- live-range-checked layout (fp16 everywhere; W buffers 96 MiB) ----
  // Phases: P0 setup | P1 G1,G2 | P2 gate | P3 tsplit,G3,G4 | P4 wgen(Wu),update
  float*  Xg1f  = (float*)(ws);                  // 16 MiB   (live P1..P4)
  float*  Xg2r  = (float*)(ws + 16777216);       // 16 MiB   (live P1..P4)
  float*  Zf    = (float*)(ws + 33554432);       // 16 MiB   (gate out, P2..P4)
  f16_t*  T1h   = (f16_t*)(ws + 33554432);       //  8 MiB overlay (P1 only: G1->G2)
  f16_t*  T1l   = (f16_t*)(ws + 41943040);       //  8 MiB overlay (P1 only)
  f16_t*  rb    = (f16_t*)(ws + 50331648);       //  8 MiB   (P2..P4)
  float*  Pg    = (float*)(ws + 58720256);       // 983040
  float*  Pu    = (float*)(ws + 59703296);       // 983040
  f16_t*  adjF  = (f16_t*)(ws + 60686336);       //  8 MiB   (P0..P3)
  f16_t*  Sh    = (f16_t*)(ws + 69074944);       //  8 MiB   (split_xt / tsplit out)
  f16_t*  Sl    = (f16_t*)(ws + 77463552);       //  8 MiB
  f16_t*  Wg    = (f16_t*)(ws + 85852160);       // 96 MiB, ends 186515456 (dead post-gate)
  f16_t*  T2h   = (f16_t*)(ws + 85852160);       //  8 MiB overlay Wg head (P3: G3->G4)
  f16_t*  T2l   = (f16_t*)(ws + 94240768);       //  8 MiB overlay (P3)
  f16_t*  Wu    = (f16_t*)(ws + 60686336);       // 96 MiB overlay adjF/S/T2/Wg-head (P4)
  float*  Cgz1f = (float*)(ws + 161349632);      // 16 MiB (old-Wg tail, P3..P4)
  float*  Cgz2r = (float*)(ws + 178126848);      // 16 MiB, ends exactly 194904064

  permute_pool<<<960, 256, 0, stream>>>(gwp, Pg, 192, 64, 128);
  permute_pool<<<960, 256, 0, stream>>>(uwp, Pu, 384, 128, 64);
  wgen<<<dim3(24, 128), 256, 0, stream>>>(Pg, emb, Wg);
  adj_softmax<<<2048, 256, 0, stream>>>(emb, adjF);
  split_xt<<<dim3(32, 32), 256, 0, stream>>>(x, Sh, Sl);

  // G1: Xg1 = adj @ X     (+ fused transposed split -> T1)
  fgemm<1><<<dim3(32, 16), 256, 0, stream>>>(adjF, Sh, Sl, Xg1f, T1h, T1l, 2048, 2048);
  // G2: Xg2 = adj @ Xg1
  fgemm<0><<<dim3(32, 16), 256, 0, stream>>>(adjF, T1h, T1l, Xg2r, nullptr, nullptr, 2048, 2048);

  gate_kernel<<<2048, 256, 0, stream>>>(x, Xg1f, Xg2r, Wg, gbp, emb, Zf, rb);

  tsplit<<<dim3(32, 32), 256, 0, stream>>>(Zf, Sh, Sl, 2048, 2048);
  // G3: Cgz1 = adj @ Z    (+ fused transposed split -> T2, in dead-Wg space)
  fgemm<1><<<dim3(32, 16), 256, 0, stream>>>(adjF, Sh, Sl, Cgz1f, T2h, T2l, 2048, 2048);
  // G4: Cgz2 = adj @ Cgz1
  fgemm<0><<<dim3(32, 16), 256, 0, stream>>>(adjF, T2h, T2l, Cgz2r, nullptr, nullptr, 2048, 2048);

  wgen<<<dim3(24, 128), 256, 0, stream>>>(Pu, emb, Wu);
  update_kernel<<<2048, 256, 0, stream>>>(x, Zf, Xg1f, Cgz1f, Xg2r, Cgz2r, Wu,
                                          ubp, emb, rb, out);
}

// Round 7
// 381.182 us; speedup vs baseline: 1.2026x; 1.1066x over previous
//
#include <hip/hip_runtime.h>

typedef _Float16 f16_t;
typedef float f32x4 __attribute__((ext_vector_type(4)));
typedef _Float16 f16x8 __attribute__((ext_vector_type(8)));

#define AS1 __attribute__((address_space(1)))
#define AS3 __attribute__((address_space(3)))

__device__ __forceinline__ void gload_lds16(const void* g, void* l) {
  __builtin_amdgcn_global_load_lds((const AS1 void*)g, (AS3 void*)l, 16, 0, 0);
}

// ------------- adj = softmax(relu(E E^T), axis=1), single fp16 plane -------
// Stored pre-scaled by 2^12 so tiny softmax entries stay out of the fp16
// denormal range; fgemm epilogue multiplies by 2^-12.
__global__ __launch_bounds__(256) void adj_softmax(const float* __restrict__ emb,
                                                   f16_t* __restrict__ adjF) {
  __shared__ float vals[2048];
  __shared__ float red[16];
  const int n = blockIdx.x;
  const int t = threadIdx.x;
  const int lane = t & 63, wave = t >> 6;
  float en[10];
#pragma unroll
  for (int e = 0; e < 10; ++e) en[e] = emb[n * 10 + e];
  float lm = 0.0f;
  for (int m = t; m < 2048; m += 256) {
    const float* em = emb + m * 10;
    float d = 0.f;
#pragma unroll
    for (int e = 0; e < 10; ++e) d += en[e] * em[e];
    d = fmaxf(d, 0.0f);
    vals[m] = d;
    lm = fmaxf(lm, d);
  }
#pragma unroll
  for (int off = 32; off > 0; off >>= 1) lm = fmaxf(lm, __shfl_down(lm, off));
  if (lane == 0) red[wave] = lm;
  __syncthreads();
  const float gmax = fmaxf(fmaxf(red[0], red[1]), fmaxf(red[2], red[3]));
  float ls = 0.f;
  for (int m = t; m < 2048; m += 256) {
    float ev = expf(vals[m] - gmax);
    vals[m] = ev;
    ls += ev;
  }
#pragma unroll
  for (int off = 32; off > 0; off >>= 1) ls += __shfl_down(ls, off);
  if (lane == 0) red[8 + wave] = ls;
  __syncthreads();
  const float inv = 4096.0f / (red[8] + red[9] + red[10] + red[11]);
  for (int m = t; m < 2048; m += 256) {
    adjF[(long)n * 2048 + m] = (f16_t)(vals[m] * inv);
  }
}

// ------------- XT[b*64+i][m] = x[b][m][i], single fp16 plane ---------------
// (lo-plane dropped: fp16 operand quantization contributes <=1e-3 to the
//  final h — see round-7 analysis; hi/lo was a bf16-era vestige.)
__global__ __launch_bounds__(256) void split_xt(const float* __restrict__ x,
                                                f16_t* __restrict__ XTh) {
  __shared__ float tile[64][65];
  const int m0 = blockIdx.x * 64;
  const int b = blockIdx.y;
  const int tx = threadIdx.x & 63, ty = threadIdx.x >> 6;
  for (int r = ty; r < 64; r += 4)
    tile[r][tx] = x[(long)b * 131072 + (long)(m0 + r) * 64 + tx];
  __syncthreads();
  for (int r = ty; r < 64; r += 4) {
    long idx = (long)(b * 64 + r) * 2048 + m0 + tx;
    XTh[idx] = (f16_t)tile[tx][r];
  }
}

// ------------- generic fp32 transpose to fp16: out[c][r] = in[r][c] --------
__global__ __launch_bounds__(256) void tsplit(const float* __restrict__ in,
                                              f16_t* __restrict__ oH, int R, int C) {
  __shared__ float tile[64][65];
  const int c0 = blockIdx.x * 64, r0 = blockIdx.y * 64;
  const int tx = threadIdx.x & 63, ty = threadIdx.x >> 6;
  for (int r = ty; r < 64; r += 4)
    tile[r][tx] = in[(long)(r0 + r) * C + c0 + tx];
  __syncthreads();
  for (int r = ty; r < 64; r += 4) {
    long idx = (long)(c0 + r) * R + r0 + tx;
    oH[idx] = (f16_t)tile[tx][r];
  }
}

// ------------- permute w_pool (E,3,I,O) -> P[e][o*KI + k*I+i], fp32 --------
__global__ __launch_bounds__(256) void permute_pool(const float* __restrict__ wp,
                                                    float* __restrict__ P,
                                                    int KI, int I, int O) {
  const int g = blockIdx.x * 256 + threadIdx.x;
  const int per = KI * O;  // 24576
  const int e = g / per, rem = g % per;
  const int o = rem / KI, kk = rem % KI;
  const int k = kk / I, i = kk % I;
  P[g] = wp[(long)((e * 3 + k) * I + i) * O + o];
}

// ------------- W[n][c] = fp16(sum_e emb[n,e] * P[e][c]) — 96 MiB out -------
// Vectorized (G13): float4 global loads hoisted to registers (reused across
// 16 nodes), ushort4 stores.
__global__ __launch_bounds__(256) void wgen(const float* __restrict__ P,
                                            const float* __restrict__ emb,
                                            f16_t* __restrict__ W) {
  __shared__ float es[160];
  const int c0 = blockIdx.x * 1024;
  const int n0 = blockIdx.y * 16;
  const int t = threadIdx.x;
  const int i4 = t * 4;
  if (t < 160) es[t] = emb[n0 * 10 + t];
  float4 p[10];
#pragma unroll
  for (int e = 0; e < 10; ++e)
    p[e] = *(const float4*)(P + (long)e * 24576 + c0 + i4);
  __syncthreads();
#pragma unroll 4
  for (int nn = 0; nn < 16; ++nn) {
    const float* ep = es + nn * 10;
    float v0 = 0.f, v1 = 0.f, v2 = 0.f, v3 = 0.f;
#pragma unroll
    for (int e = 0; e < 10; ++e) {
      const float ee = ep[e];
      v0 += ee * p[e].x; v1 += ee * p[e].y; v2 += ee * p[e].z; v3 += ee * p[e].w;
    }
    union { ushort4 u; f16_t h[4]; } o;
    o.h[0] = (f16_t)v0; o.h[1] = (f16_t)v1; o.h[2] = (f16_t)v2; o.h[3] = (f16_t)v3;
    *(ushort4*)(W + (long)(n0 + nn) * 24576 + c0 + i4) = o.u;
  }
}

// ------------- unified fused GEMM (fp16), single-plane ---------------------
// R1-proven structure (128Mx64N, 4 waves of 32Mx64N, BK=64, XOR-swizzled
// LDS, single-buffered 2-barrier loop, 2 blocks/CU) with the lo B-plane
// dropped: 16 MFMA + 6 gloads per K-step (was 32 + 8).  A = adj single fp16
// plane (pre-scaled 2^12); epilogue multiplies 2^-12.
// WT: also emit transposed fp16 C (next GEMM's B operand).
template <int WT>
__global__ __launch_bounds__(256) void fgemm(const f16_t* __restrict__ A,
                                             const f16_t* __restrict__ B,
                                             float* __restrict__ Cf,
                                             f16_t* __restrict__ Th,
                                             int K, int ldc) {
  __shared__ __align__(16) f16_t Ash[128 * 64];
  __shared__ __align__(16) f16_t Bsh[64 * 64];
  const int t = threadIdx.x;
  const int wave = t >> 6, lane = t & 63;
  const long m0 = (long)blockIdx.y * 128;
  const long n0 = (long)blockIdx.x * 64;
  const int srow = t >> 3;
  const int sc8 = ((t & 7) ^ (srow & 7)) << 3;
  const int fr = lane & 15;
  const int quad = lane >> 4;
  const int wm = wave * 32;
  char* lA = (char*)Ash + wave * 1024;
  char* lB = (char*)Bsh + wave * 1024;
  f32x4 acc[2][4] = {};
  for (int k0 = 0; k0 < K; k0 += 64) {
#pragma unroll
    for (int q = 0; q < 4; ++q)
      gload_lds16(A + (m0 + q * 32 + srow) * K + k0 + sc8, lA + q * 4096);
#pragma unroll
    for (int q = 0; q < 2; ++q)
      gload_lds16(B + (n0 + q * 32 + srow) * K + k0 + sc8, lB + q * 4096);
    __syncthreads();
#pragma unroll
    for (int kh = 0; kh < 2; ++kh) {
      const int cbase = kh * 4 + quad;
      f16x8 ah[2], bh[4];
#pragma unroll
      for (int i = 0; i < 2; ++i) {
        const int r = wm + i * 16 + fr;
        ah[i] = *(const f16x8*)(Ash + r * 64 + ((cbase ^ (fr & 7)) << 3));
      }
#pragma unroll
      for (int j = 0; j < 4; ++j) {
        const int r = j * 16 + fr;
        bh[j] = *(const f16x8*)(Bsh + r * 64 + ((cbase ^ (fr & 7)) << 3));
      }
#pragma unroll
      for (int i = 0; i < 2; ++i)
#pragma unroll
        for (int j = 0; j < 4; ++j)
          acc[i][j] = __builtin_amdgcn_mfma_f32_16x16x32_f16(ah[i], bh[j], acc[i][j], 0, 0, 0);
    }
    __syncthreads();
  }
  const int crow = quad * 4, ccol = fr;
#pragma unroll
  for (int i = 0; i < 2; ++i)
#pragma unroll
    for (int j = 0; j < 4; ++j) {
      float v[4];
#pragma unroll
      for (int r = 0; r < 4; ++r) v[r] = acc[i][j][r] * 0.000244140625f;  // 2^-12
      const long gmb = m0 + wm + i * 16 + crow;
      const long gn = n0 + j * 16 + ccol;
#pragma unroll
      for (int r = 0; r < 4; ++r) Cf[(gmb + r) * ldc + gn] = v[r];
      if (WT) {
        union { ushort4 u; f16_t h[4]; } ph;
#pragma unroll
        for (int r = 0; r < 4; ++r) ph.h[r] = (f16_t)v[r];
        *(ushort4*)(Th + gn * 2048 + gmb) = ph.u;
      }
    }
}

// ------------- gate: one block per node n (grid 2048) ----------------------
// Single-plane A staging (lo dropped), 4 MFMA per K-step (was 8).
__global__ __launch_bounds__(256) void gate_kernel(
    const float* __restrict__ x, const float* __restrict__ Xg1f,
    const float* __restrict__ Xg2r, const f16_t* __restrict__ Wg,
    const float* __restrict__ bpool, const float* __restrict__ emb,
    float* __restrict__ Zf, f16_t* __restrict__ rb) {
  __shared__ __align__(16) f16_t Ahi[32 * 200];
  const int n = blockIdx.x;
  const int t = threadIdx.x;
  float en[10];
#pragma unroll
  for (int e = 0; e < 10; ++e) en[e] = emb[n * 10 + e];
  {
    const int b = t >> 3, i8 = (t & 7) * 8;
    const float* s0 = x + (long)b * 131072 + (long)n * 64 + i8;
    const float* s1 = Xg1f + (long)n * 2048 + b * 64 + i8;
    const float* s2 = Xg2r + (long)n * 2048 + b * 64 + i8;
    float v0[8], v1[8], v2[8];
#pragma unroll
    for (int j = 0; j < 8; ++j) v0[j] = s0[j];
#pragma unroll
    for (int j = 0; j < 8; ++j) v1[j] = s1[j];
#pragma unroll
    for (int j = 0; j < 8; ++j) v2[j] = 2.0f * s2[j] - v0[j];
    union { uint4 u; f16_t h[8]; } th;
#pragma unroll
    for (int j = 0; j < 8; ++j) th.h[j] = (f16_t)v0[j];
    *(uint4*)(Ahi + b * 200 + i8) = th.u;
#pragma unroll
    for (int j = 0; j < 8; ++j) th.h[j] = (f16_t)v1[j];
    *(uint4*)(Ahi + b * 200 + 64 + i8) = th.u;
#pragma unroll
    for (int j = 0; j < 8; ++j) th.h[j] = (f16_t)v2[j];
    *(uint4*)(Ahi + b * 200 + 128 + i8) = th.u;
  }
  __syncthreads();
  const int wave = t >> 6, lane = t & 63;
  const int ob = wave * 32;
  const int fr = lane & 15, qk = (lane >> 4) * 8;
  const f16_t* Wp0 = Wg + (long)n * 24576 + (ob + fr) * 192 + qk;
  const f16_t* Wp1 = Wp0 + 16 * 192;
  f32x4 acc[2][2] = {};
#pragma unroll
  for (int k0 = 0; k0 < 192; k0 += 32) {
    f16x8 b0 = *(const f16x8*)(Wp0 + k0);
    f16x8 b1 = *(const f16x8*)(Wp1 + k0);
    f16x8 a0 = *(const f16x8*)(Ahi + fr * 200 + k0 + qk);
    f16x8 a1 = *(const f16x8*)(Ahi + (16 + fr) * 200 + k0 + qk);
    acc[0][0] = __builtin_amdgcn_mfma_f32_16x16x32_f16(a0, b0, acc[0][0], 0, 0, 0);
    acc[1][0] = __builtin_amdgcn_mfma_f32_16x16x32_f16(a1, b0, acc[1][0], 0, 0, 0);
    acc[0][1] = __builtin_amdgcn_mfma_f32_16x16x32_f16(a0, b1, acc[0][1], 0, 0, 0);
    acc[1][1] = __builtin_amdgcn_mfma_f32_16x16x32_f16(a1, b1, acc[1][1], 0, 0, 0);
  }
  const int quad = lane >> 4;
#pragma unroll
  for (int j = 0; j < 2; ++j) {
    const int o = ob + j * 16 + fr;   // 0..127
    float bias = 0.f;
#pragma unroll
    for (int e = 0; e < 10; ++e) bias += en[e] * bpool[e * 128 + o];
#pragma unroll
    for (int i2 = 0; i2 < 2; ++i2)
#pragma unroll
      for (int r = 0; r < 4; ++r) {
        const int b = i2 * 16 + quad * 4 + r;
        float v = acc[i2][j][r] + bias;
        v = 1.0f / (1.0f + expf(-v));
        if (o < 64)
          Zf[(long)n * 2048 + b * 64 + o] = v;
        else
          rb[(long)n * 2048 + b * 64 + (o - 64)] = (f16_t)v;
      }
  }
}

// ------------- update: one block per node n (grid 2048) --------------------
// Single-plane A staging (lo dropped), 2 MFMA per K-step (was 4).
__global__ __launch_bounds__(256) void update_kernel(
    const float* __restrict__ x, const float* __restrict__ Zf,
    const float* __restrict__ Xg1f, const float* __restrict__ Cgz1f,
    const float* __restrict__ Xg2r, const float* __restrict__ Cgz2r,
    const f16_t* __restrict__ Wu, const float* __restrict__ bpool,
    const float* __restrict__ emb, const f16_t* __restrict__ rb,
    float* __restrict__ out) {
  __shared__ __align__(16) f16_t Ahi[32 * 392];
  const int n = blockIdx.x;
  const int t = threadIdx.x;
  float en[10];
#pragma unroll
  for (int e = 0; e < 10; ++e) en[e] = emb[n * 10 + e];
#pragma unroll
  for (int r = 0; r < 2; ++r) {
    const int c = r * 2048 + t * 8;  // (b, j) over 32 x 128
    const int b = c >> 7, j = c & 127;
    const int lo64 = j & 63;
    const float* s0 = (j < 64) ? (x + (long)b * 131072 + (long)n * 64 + lo64)
                               : (Zf + (long)n * 2048 + b * 64 + lo64);
    const float* s1 = (j < 64) ? (Xg1f + (long)n * 2048 + b * 64 + lo64)
                               : (Cgz1f + (long)n * 2048 + b * 64 + lo64);
    const float* s2 = (j < 64) ? (Xg2r + (long)n * 2048 + b * 64 + lo64)
                               : (Cgz2r + (long)n * 2048 + b * 64 + lo64);
    float v0[8], v1[8], v2[8];
#pragma unroll
    for (int q = 0; q < 8; ++q) v0[q] = s0[q];
#pragma unroll
    for (int q = 0; q < 8; ++q) v1[q] = s1[q];
#pragma unroll
    for (int q = 0; q < 8; ++q) v2[q] = 2.0f * s2[q] - v0[q];
    union { uint4 u; f16_t h[8]; } th;
#pragma unroll
    for (int q = 0; q < 8; ++q) th.h[q] = (f16_t)v0[q];
    *(uint4*)(Ahi + b * 392 + j) = th.u;
#pragma unroll
    for (int q = 0; q < 8; ++q) th.h[q] = (f16_t)v1[q];
    *(uint4*)(Ahi + b * 392 + 128 + j) = th.u;
#pragma unroll
    for (int q = 0; q < 8; ++q) th.h[q] = (f16_t)v2[q];
    *(uint4*)(Ahi + b * 392 + 256 + j) = th.u;
  }
  __syncthreads();
  const int wave = t >> 6, lane = t & 63;
  const int ob = wave * 16;            // 64 o across 4 waves
  const int fr = lane & 15, qk = (lane >> 4) * 8;
  const f16_t* Wp = Wu + (long)n * 24576 + (ob + fr) * 384 + qk;
  f32x4 acc[2] = {};
#pragma unroll
  for (int k0 = 0; k0 < 384; k0 += 32) {
    f16x8 bhv = *(const f16x8*)(Wp + k0);
    f16x8 a0 = *(const f16x8*)(Ahi + fr * 392 + k0 + qk);
    f16x8 a1 = *(const f16x8*)(Ahi + (16 + fr) * 392 + k0 + qk);
    acc[0] = __builtin_amdgcn_mfma_f32_16x16x32_f16(a0, bhv, acc[0], 0, 0, 0);
    acc[1] = __builtin_amdgcn_mfma_f32_16x16x32_f16(a1, bhv, acc[1], 0, 0, 0);
  }
  const int quad = lane >> 4;
  const int og = ob + fr;
  float bias = 0.f;
#pragma unroll
  for (int e = 0; e < 10; ++e) bias += en[e] * bpool[e * 64 + og];
#pragma unroll
  for (int i2 = 0; i2 < 2; ++i2)
#pragma unroll
    for (int r = 0; r < 4; ++r) {
      const int b = i2 * 16 + quad * 4 + r;
      float hc = tanhf(acc[i2][r] + bias);
      float rr = (float)rb[(long)n * 2048 + b * 64 + og];
      float xv = x[(long)b * 131072 + (long)n * 64 + og];
      out[(long)b * 131072 + (long)n * 64 + og] = rr * xv + (1.0f - rr) * hc;
    }
}

extern "C" void kernel_launch(void* const* d_in, const int* in_sizes, int n_in,
                              void* d_out, int out_size, void* d_ws, size_t ws_size,
                              hipStream_t stream) {
  (void)in_sizes; (void)n_in; (void)out_size;
  const float* x   = (const float*)d_in[0];
  const float* emb = (const float*)d_in[2];
  const float* gwp = (const float*)d_in[3];
  const float* gbp = (const float*)d_in[4];
  const float* uwp = (const float*)d_in[5];
  const float* ubp = (const float*)d_in[6];
  float* out = (float*)d_out;
  char* ws = (char*)d_ws;

  // high-water 194,904,064 B (layout unchanged; lo-plane slots now unused).
  if (ws_size < 194904064ull) return;

  // Phases: P0 setup | P1 G1,G2 | P2 gate | P3 tsplit,G3,G4 | P4 wgen(Wu),update
  float*  Xg1f  = (float*)(ws);                  // 16 MiB   (live P1..P4)
  float*  Xg2r  = (float*)(ws + 16777216);       // 16 MiB   (live P1..P4)
  float*  Zf    = (float*)(ws + 33554432);       // 16 MiB   (gate out, P2..P4)
  f16_t*  T1h   = (f16_t*)(ws + 33554432);       //  8 MiB overlay (P1 only: G1->G2)
  f16_t*  rb    = (f16_t*)(ws + 50331648);       //  8 MiB   (P2..P4)
  float*  Pg    = (float*)(ws + 58720256);       // 983040
  float*  Pu    = (float*)(ws + 59703296);       // 983040
  f16_t*  adjF  = (f16_t*)(ws + 60686336);       //  8 MiB   (P0..P3)
  f16_t*  Sh    = (f16_t*)(ws + 69074944);       //  8 MiB   (split_xt / tsplit out)
  f16_t*  Wg    = (f16_t*)(ws + 85852160);       // 96 MiB   (dead post-gate)
  f16_t*  T2h   = (f16_t*)(ws + 85852160);       //  8 MiB overlay Wg head (P3: G3->G4)
  f16_t*  Wu    = (f16_t*)(ws + 60686336);       // 96 MiB overlay adjF/Sh/T2/Wg-head (P4)
  float*  Cgz1f = (float*)(ws + 161349632);      // 16 MiB (old-Wg tail, P3..P4)
  float*  Cgz2r = (float*)(ws + 178126848);      // 16 MiB, ends exactly 194904064

  permute_pool<<<960, 256, 0, stream>>>(gwp, Pg, 192, 64, 128);
  permute_pool<<<960, 256, 0, stream>>>(uwp, Pu, 384, 128, 64);
  wgen<<<dim3(24, 128), 256, 0, stream>>>(Pg, emb, Wg);
  adj_softmax<<<2048, 256, 0, stream>>>(emb, adjF);
  split_xt<<<dim3(32, 32), 256, 0, stream>>>(x, Sh);

  // G1: Xg1 = adj @ X     (+ fused transposed fp16 C -> T1)
  fgemm<1><<<dim3(32, 16), 256, 0, stream>>>(adjF, Sh, Xg1f, T1h, 2048, 2048);
  // G2: Xg2 = adj @ Xg1
  fgemm<0><<<dim3(32, 16), 256, 0, stream>>>(adjF, T1h, Xg2r, nullptr, 2048, 2048);

  gate_kernel<<<2048, 256, 0, stream>>>(x, Xg1f, Xg2r, Wg, gbp, emb, Zf, rb);

  tsplit<<<dim3(32, 32), 256, 0, stream>>>(Zf, Sh, 2048, 2048);
  // G3: Cgz1 = adj @ Z    (+ fused transposed fp16 C -> T2, in dead-Wg space)
  fgemm<1><<<dim3(32, 16), 256, 0, stream>>>(adjF, Sh, Cgz1f, T2h, 2048, 2048);
  // G4: Cgz2 = adj @ Cgz1
  fgemm<0><<<dim3(32, 16), 256, 0, stream>>>(adjF, T2h, Cgz2r, nullptr, 2048, 2048);

  wgen<<<dim3(24, 128), 256, 0, stream>>>(Pu, emb, Wu);
  update_kernel<<<2048, 256, 0, stream>>>(x, Zf, Xg1f, Cgz1f, Xg2r, Cgz2r, Wu,
                                          ubp, emb, rb, out);
}